// Round 1
// baseline (151.281 us; speedup 1.0000x reference)
//
#include <hip/hip_runtime.h>
#include <cstddef>

#define B_   8
#define H_   96
#define W_   96
#define HW_  9216
#define PIX_ 73728

typedef __attribute__((ext_vector_type(8))) __bf16 bf16x8;
typedef __attribute__((ext_vector_type(4))) float floatx4;
typedef __attribute__((ext_vector_type(2))) float floatx2;

// ws layout (byte offsets)
#define XT_OFF   0                          // bf16 NHWC x: PIX*64*2
#define WFM_OFF  (XT_OFF + PIX_*64*2)       // main W frags: 18*4*64*8 bf16
#define WFO_OFF  (WFM_OFF + 18*4*64*8*2)    // offs W frags: 18*2*64*8 bf16

__device__ __forceinline__ unsigned short f2bf(float f) {
    unsigned u = __float_as_uint(f);
    return (unsigned short)((u + 0x7FFFu + ((u >> 16) & 1u)) >> 16);
}

__device__ __forceinline__ floatx2 unpk2(unsigned u) {
    union { unsigned ui[2]; floatx2 f; } t;
    t.ui[0] = u << 16;
    t.ui[1] = u & 0xffff0000u;
    return t.f;
}

__device__ __forceinline__ unsigned cvt_pk_bf16(float lo, float hi) {
    unsigned r;
    asm("v_cvt_pk_bf16_f32 %0, %1, %2" : "=v"(r) : "v"(lo), "v"(hi));
    return r;
}

// ---------------------------------------------------------------------------
// NCHW f32 -> NHWC bf16 transpose via LDS tile
__global__ __launch_bounds__(256) void k_transpose(const float* __restrict__ x,
                                                   unsigned short* __restrict__ xt) {
    __shared__ float tile[64 * 65];
    int bb  = blockIdx.x / 144;
    int sp0 = (blockIdx.x % 144) * 64;
    int t = threadIdx.x;
    int s = t & 63, cg = t >> 6;
    #pragma unroll
    for (int i = 0; i < 16; ++i) {
        int c = cg * 16 + i;
        tile[c * 65 + s] = x[(size_t)(bb * 64 + c) * HW_ + sp0 + s];
    }
    __syncthreads();
    int cl4 = (t & 15) * 4, sg = t >> 4;
    #pragma unroll
    for (int i = 0; i < 4; ++i) {
        int s2 = sg * 4 + i;
        uint2 wd;
        wd.x = (unsigned)f2bf(tile[cl4 * 65 + s2])       | ((unsigned)f2bf(tile[(cl4 + 1) * 65 + s2]) << 16);
        wd.y = (unsigned)f2bf(tile[(cl4 + 2) * 65 + s2]) | ((unsigned)f2bf(tile[(cl4 + 3) * 65 + s2]) << 16);
        *(uint2*)(xt + (size_t)(bb * HW_ + sp0 + s2) * 64 + cl4) = wd;
    }
}

// ---------------------------------------------------------------------------
// Pack weights into MFMA A-fragment order (k = tap*64 + c).
__global__ __launch_bounds__(256) void k_prepw(const float* __restrict__ offw,
                                               const float* __restrict__ mw,
                                               const float* __restrict__ convw,
                                               unsigned short* __restrict__ wfm,
                                               unsigned short* __restrict__ wfo) {
    int g = blockIdx.x * 256 + threadIdx.x;
    if (g < 4608) {
        int lane = g & 63, mtks = g >> 6;
        int mt = mtks & 3, ks = mtks >> 2;
        int o = mt * 16 + (lane & 15), quad = lane >> 4;
        unsigned v[8];
        #pragma unroll
        for (int j = 0; j < 8; ++j) {
            int k = ks * 32 + quad * 8 + j;
            int t = k / 64, c = k % 64;
            v[j] = f2bf(convw[(size_t)(o * 64 + c) * 9 + t]);
        }
        uint4 pk;
        pk.x = v[0] | (v[1] << 16); pk.y = v[2] | (v[3] << 16);
        pk.z = v[4] | (v[5] << 16); pk.w = v[6] | (v[7] << 16);
        *(uint4*)(wfm + (size_t)g * 8) = pk;
    } else if (g < 4608 + 2304) {
        int g2 = g - 4608;
        int lane = g2 & 63, mtks = g2 >> 6;
        int mt = mtks & 1, ks = mtks >> 1;
        int m = mt * 16 + (lane & 15), quad = lane >> 4;
        unsigned v[8];
        #pragma unroll
        for (int j = 0; j < 8; ++j) {
            int k = ks * 32 + quad * 8 + j;
            int t = k / 64, c = k % 64;
            float f = 0.f;
            if (m < 18)      f = offw[(size_t)(m * 64 + c) * 9 + t];
            else if (m < 27) f = mw[(size_t)((m - 18) * 64 + c) * 9 + t];
            v[j] = f2bf(f);
        }
        uint4 pk;
        pk.x = v[0] | (v[1] << 16); pk.y = v[2] | (v[3] << 16);
        pk.z = v[4] | (v[5] << 16); pk.w = v[6] | (v[7] << 16);
        *(uint4*)(wfo + (size_t)g2 * 8) = pk;
    }
}

// ---------------------------------------------------------------------------
// Combine 4 gathered bilinear corners (packed-pair f32 math) and feed 4 MFMAs.
__device__ __forceinline__ void combine_mfma(const unsigned short* __restrict__ wfm,
                                             int lane, int ks,
                                             uint4 g0, uint4 g1, uint4 g2, uint4 g3,
                                             floatx2 w0, floatx2 w1, floatx2 w2, floatx2 w3,
                                             floatx4* acc) {
    bf16x8 af0 = *(const bf16x8*)(wfm + ((size_t)(ks * 4 + 0) * 64 + lane) * 8);
    bf16x8 af1 = *(const bf16x8*)(wfm + ((size_t)(ks * 4 + 1) * 64 + lane) * 8);
    bf16x8 af2 = *(const bf16x8*)(wfm + ((size_t)(ks * 4 + 2) * 64 + lane) * 8);
    bf16x8 af3 = *(const bf16x8*)(wfm + ((size_t)(ks * 4 + 3) * 64 + lane) * 8);
    uint4 pk;
    {
        floatx2 v = w0 * unpk2(g0.x);
        v += w1 * unpk2(g1.x); v += w2 * unpk2(g2.x); v += w3 * unpk2(g3.x);
        pk.x = cvt_pk_bf16(v[0], v[1]);
    }
    {
        floatx2 v = w0 * unpk2(g0.y);
        v += w1 * unpk2(g1.y); v += w2 * unpk2(g2.y); v += w3 * unpk2(g3.y);
        pk.y = cvt_pk_bf16(v[0], v[1]);
    }
    {
        floatx2 v = w0 * unpk2(g0.z);
        v += w1 * unpk2(g1.z); v += w2 * unpk2(g2.z); v += w3 * unpk2(g3.z);
        pk.z = cvt_pk_bf16(v[0], v[1]);
    }
    {
        floatx2 v = w0 * unpk2(g0.w);
        v += w1 * unpk2(g1.w); v += w2 * unpk2(g2.w); v += w3 * unpk2(g3.w);
        pk.w = cvt_pk_bf16(v[0], v[1]);
    }
    union { uint4 u; bf16x8 b; } ub; ub.u = pk;
    acc[0] = __builtin_amdgcn_mfma_f32_16x16x32_bf16(af0, ub.b, acc[0], 0, 0, 0);
    acc[1] = __builtin_amdgcn_mfma_f32_16x16x32_bf16(af1, ub.b, acc[1], 0, 0, 0);
    acc[2] = __builtin_amdgcn_mfma_f32_16x16x32_bf16(af2, ub.b, acc[2], 0, 0, 0);
    acc[3] = __builtin_amdgcn_mfma_f32_16x16x32_bf16(af3, ub.b, acc[3], 0, 0, 0);
}

// ---------------------------------------------------------------------------
// Fused: offset/mod conv (MFMA) -> bilinear meta -> main contraction (MFMA).
// One wave owns 16 pixels. 4608 waves (4.5/SIMD). Software-pipelined gathers.
__global__ __launch_bounds__(128, 4) void k_fused(const unsigned short* __restrict__ xt,
                                                  const unsigned short* __restrict__ wfo,
                                                  const unsigned short* __restrict__ wfm,
                                                  const float* __restrict__ offb,
                                                  const float* __restrict__ mb,
                                                  const float* __restrict__ convb,
                                                  float* __restrict__ out) {
    __shared__ float s_off[2][32 * 17];     // [wave][m][pix] (stride 17)
    __shared__ float s_meta[2][16 * 76];    // [wave][pix][n][8 words] (stride 76, 16B-aligned)
    int tid = threadIdx.x;
    int w = tid >> 6, lane = tid & 63, col = lane & 15, quad = lane >> 4;
    int q8 = quad * 8;
    int pix0 = blockIdx.x * 32 + w * 16;
    int b  = pix0 / HW_;
    int sb = pix0 % HW_;
    const unsigned short* xtb = xt + (size_t)b * HW_ * 64;

    int sp = sb + col;
    int hh = sp / 96, ww = sp % 96;

    // ---- phase 1: offset/mod conv GEMM (M=32, K=576), B prefetched 1 tap ahead ----
    floatx4 aoff0 = (floatx4){0.f, 0.f, 0.f, 0.f};
    floatx4 aoff1 = (floatx4){0.f, 0.f, 0.f, 0.f};
    uint4 zero4 = make_uint4(0, 0, 0, 0);
    uint4 bv0, bv1;
    {
        int h2 = hh - 1, w2 = ww - 1;
        bool ok = ((unsigned)h2 < 96u) && ((unsigned)w2 < 96u);
        int ofs = (h2 * 96 + w2) * 64 + q8;
        bv0 = ok ? *(const uint4*)(xtb + ofs)      : zero4;
        bv1 = ok ? *(const uint4*)(xtb + ofs + 32) : zero4;
    }
    #pragma unroll 1
    for (int t = 0; t < 9; ++t) {
        bf16x8 a00 = *(const bf16x8*)(wfo + ((size_t)(4 * t + 0) * 64 + lane) * 8);
        bf16x8 a01 = *(const bf16x8*)(wfo + ((size_t)(4 * t + 1) * 64 + lane) * 8);
        bf16x8 a10 = *(const bf16x8*)(wfo + ((size_t)(4 * t + 2) * 64 + lane) * 8);
        bf16x8 a11 = *(const bf16x8*)(wfo + ((size_t)(4 * t + 3) * 64 + lane) * 8);
        uint4 nb0 = zero4, nb1 = zero4;
        if (t < 8) {
            int tn = t + 1;
            int h2 = hh + tn / 3 - 1, w2 = ww + tn % 3 - 1;
            bool ok = ((unsigned)h2 < 96u) && ((unsigned)w2 < 96u);
            int ofs = (h2 * 96 + w2) * 64 + q8;
            if (ok) {
                nb0 = *(const uint4*)(xtb + ofs);
                nb1 = *(const uint4*)(xtb + ofs + 32);
            }
        }
        union { uint4 u; bf16x8 b; } u0, u1; u0.u = bv0; u1.u = bv1;
        aoff0 = __builtin_amdgcn_mfma_f32_16x16x32_bf16(a00, u0.b, aoff0, 0, 0, 0);
        aoff1 = __builtin_amdgcn_mfma_f32_16x16x32_bf16(a01, u0.b, aoff1, 0, 0, 0);
        aoff0 = __builtin_amdgcn_mfma_f32_16x16x32_bf16(a10, u1.b, aoff0, 0, 0, 0);
        aoff1 = __builtin_amdgcn_mfma_f32_16x16x32_bf16(a11, u1.b, aoff1, 0, 0, 0);
        bv0 = nb0; bv1 = nb1;
    }
    #pragma unroll
    for (int r = 0; r < 4; ++r) {
        s_off[w][( 0 + quad * 4 + r) * 17 + col] = aoff0[r];
        s_off[w][(16 + quad * 4 + r) * 17 + col] = aoff1[r];
    }
    __syncthreads();

    // ---- phase 2: bilinear metadata (16 px x 9 n per wave, all 64 lanes) ----
    {
        int gsel = lane >> 4, pp = lane & 15;
        int sP = sb + pp, phh = sP / 96, pww = sP % 96;
        #pragma unroll
        for (int i = 0; i < 3; ++i) {
            int n = gsel + 4 * i;
            if (n < 9) {
                float ox = s_off[w][n * 17 + pp]        + offb[n];
                float oy = s_off[w][(9 + n) * 17 + pp]  + offb[9 + n];
                float mv = s_off[w][(18 + n) * 17 + pp] + mb[n];
                float mod = 1.f / (1.f + __expf(-mv));
                float px = ox + (float)(phh + 1) + (float)(n / 3 - 1);
                float py = oy + (float)(pww + 1) + (float)(n % 3 - 1);
                float flx = floorf(px), fly = floorf(py);
                float tlxf = fminf(fmaxf(flx,       0.f), 97.f);
                float tlyf = fminf(fmaxf(fly,       0.f), 97.f);
                float brxf = fminf(fmaxf(flx + 1.f, 0.f), 97.f);
                float bryf = fminf(fmaxf(fly + 1.f, 0.f), 97.f);
                float pcx  = fminf(fmaxf(px, 0.f), 97.f);
                float pcy  = fminf(fmaxf(py, 0.f), 97.f);
                float gx0 = 1.f + tlxf - pcx;
                float gx1 = 1.f - (brxf - pcx);
                float gy0 = 1.f + tlyf - pcy;
                float gy1 = 1.f - (bryf - pcy);
                int tlx = (int)tlxf, tly = (int)tlyf, brx = (int)brxf, bry = (int)bryf;
                int   qxs[4] = {tlx, tlx, brx, brx};
                int   qys[4] = {tly, bry, tly, bry};
                float gs[4]  = {gx0 * gy0, gx0 * gy1, gx1 * gy0, gx1 * gy1};
                int   idx[4]; float gg[4];
                #pragma unroll
                for (int c4 = 0; c4 < 4; ++c4) {
                    bool okc = (qxs[c4] >= 1) && (qxs[c4] <= 96) && (qys[c4] >= 1) && (qys[c4] <= 96);
                    idx[c4] = okc ? ((qxs[c4] - 1) * W_ + (qys[c4] - 1)) : 0;
                    gg[c4]  = okc ? gs[c4] * mod : 0.f;
                }
                int4 ivv;  ivv.x = idx[0]; ivv.y = idx[1]; ivv.z = idx[2]; ivv.w = idx[3];
                float4 gvv; gvv.x = gg[0]; gvv.y = gg[1]; gvv.z = gg[2]; gvv.w = gg[3];
                *(int4*)  &s_meta[w][pp * 76 + n * 8]     = ivv;
                *(float4*)&s_meta[w][pp * 76 + n * 8 + 4] = gvv;
            }
        }
    }
    __syncthreads();

    // ---- phase 3: main contraction GEMM (M=64, K=576), pipelined gathers ----
    floatx4 acc[4];
    #pragma unroll
    for (int mt = 0; mt < 4; ++mt) acc[mt] = (floatx4){0.f, 0.f, 0.f, 0.f};

    const float* mrow = &s_meta[w][col * 76];
    int4   iv = *(const int4*)(mrow);
    float4 gv = *(const float4*)(mrow + 4);
    uint4 gA0 = *(const uint4*)(xtb + (size_t)iv.x * 64 + q8);
    uint4 gA1 = *(const uint4*)(xtb + (size_t)iv.y * 64 + q8);
    uint4 gA2 = *(const uint4*)(xtb + (size_t)iv.z * 64 + q8);
    uint4 gA3 = *(const uint4*)(xtb + (size_t)iv.w * 64 + q8);

    #pragma unroll 1
    for (int n = 0; n < 9; ++n) {
        // issue ksl=1 gathers for current n
        uint4 gB0 = *(const uint4*)(xtb + (size_t)iv.x * 64 + 32 + q8);
        uint4 gB1 = *(const uint4*)(xtb + (size_t)iv.y * 64 + 32 + q8);
        uint4 gB2 = *(const uint4*)(xtb + (size_t)iv.z * 64 + 32 + q8);
        uint4 gB3 = *(const uint4*)(xtb + (size_t)iv.w * 64 + 32 + q8);
        // prefetch next n's metadata (LDS)
        int4 ivn = iv; float4 gvn = gv;
        if (n < 8) {
            ivn = *(const int4*)(mrow + (n + 1) * 8);
            gvn = *(const float4*)(mrow + (n + 1) * 8 + 4);
        }
        floatx2 w0 = {gv.x, gv.x}, w1 = {gv.y, gv.y}, w2 = {gv.z, gv.z}, w3 = {gv.w, gv.w};
        combine_mfma(wfm, lane, 2 * n, gA0, gA1, gA2, gA3, w0, w1, w2, w3, acc);
        // issue next n's ksl=0 gathers while ksl=1 data is being combined
        if (n < 8) {
            gA0 = *(const uint4*)(xtb + (size_t)ivn.x * 64 + q8);
            gA1 = *(const uint4*)(xtb + (size_t)ivn.y * 64 + q8);
            gA2 = *(const uint4*)(xtb + (size_t)ivn.z * 64 + q8);
            gA3 = *(const uint4*)(xtb + (size_t)ivn.w * 64 + q8);
        }
        combine_mfma(wfm, lane, 2 * n + 1, gB0, gB1, gB2, gB3, w0, w1, w2, w3, acc);
        iv = ivn; gv = gvn;
    }

    // ---- epilogue ----
    #pragma unroll
    for (int mt = 0; mt < 4; ++mt) {
        float4 cb4 = *(const float4*)&convb[mt * 16 + quad * 4];
        #pragma unroll
        for (int r = 0; r < 4; ++r) {
            int o = mt * 16 + quad * 4 + r;
            float bias = (r == 0) ? cb4.x : (r == 1) ? cb4.y : (r == 2) ? cb4.z : cb4.w;
            out[(size_t)(b * 64 + o) * HW_ + sb + col] = acc[mt][r] + bias;
        }
    }
}

// ---------------------------------------------------------------------------
extern "C" void kernel_launch(void* const* d_in, const int* in_sizes, int n_in,
                              void* d_out, int out_size, void* d_ws, size_t ws_size,
                              hipStream_t stream) {
    const float* x     = (const float*)d_in[0];
    const float* offw  = (const float*)d_in[1];
    const float* offb  = (const float*)d_in[2];
    const float* mw    = (const float*)d_in[3];
    const float* mb    = (const float*)d_in[4];
    const float* convw = (const float*)d_in[5];
    const float* convb = (const float*)d_in[6];
    char* ws = (char*)d_ws;
    unsigned short* xt16 = (unsigned short*)(ws + XT_OFF);
    unsigned short* wfm  = (unsigned short*)(ws + WFM_OFF);
    unsigned short* wfo  = (unsigned short*)(ws + WFO_OFF);
    float* out = (float*)d_out;

    k_transpose<<<dim3(1152), dim3(256), 0, stream>>>(x, xt16);
    k_prepw    <<<dim3(27),   dim3(256), 0, stream>>>(offw, mw, convw, wfm, wfo);
    k_fused    <<<dim3(2304), dim3(128), 0, stream>>>(xt16, wfo, wfm, offb, mb, convb, out);
}

// Round 2
// 135.923 us; speedup vs baseline: 1.1130x; 1.1130x over previous
//
#include <hip/hip_runtime.h>
#include <hip/hip_fp16.h>
#include <cstddef>

#define B_   8
#define H_   96
#define W_   96
#define HW_  9216
#define PIX_ 73728

// LDS window geometry: rows hr-3..hr+5 (9), cols wc-4..wc+35 (40)
#define NWR    9
#define NWC    40
#define WINPX  360
#define NSLOTS 16

typedef __attribute__((ext_vector_type(8))) __bf16 bf16x8;
typedef __attribute__((ext_vector_type(4))) float floatx4;
typedef __attribute__((ext_vector_type(2))) float floatx2;

// ws layout (byte offsets)
#define XT_OFF   0                          // bf16 NHWC x: PIX*64*2
#define WFM_OFF  (XT_OFF + PIX_*64*2)       // main W frags: 18*4*64*8 bf16
#define WFO_OFF  (WFM_OFF + 18*4*64*8*2)    // offs W frags: 18*2*64*8 bf16

__device__ __forceinline__ unsigned short f2bf(float f) {
    unsigned u = __float_as_uint(f);
    return (unsigned short)((u + 0x7FFFu + ((u >> 16) & 1u)) >> 16);
}

__device__ __forceinline__ floatx2 unpk2(unsigned u) {
    union { unsigned ui[2]; floatx2 f; } t;
    t.ui[0] = u << 16;
    t.ui[1] = u & 0xffff0000u;
    return t.f;
}

__device__ __forceinline__ unsigned cvt_pk_bf16(float lo, float hi) {
    unsigned r;
    asm("v_cvt_pk_bf16_f32 %0, %1, %2" : "=v"(r) : "v"(lo), "v"(hi));
    return r;
}

// Combine 4 gathered bilinear corners (packed-pair f32 math) -> 8 bf16.
__device__ __forceinline__ uint4 combine4(uint4 c0, uint4 c1, uint4 c2, uint4 c3,
                                          floatx2 w0, floatx2 w1, floatx2 w2, floatx2 w3) {
    uint4 pk;
    { floatx2 v = w0 * unpk2(c0.x); v += w1 * unpk2(c1.x); v += w2 * unpk2(c2.x); v += w3 * unpk2(c3.x);
      pk.x = cvt_pk_bf16(v[0], v[1]); }
    { floatx2 v = w0 * unpk2(c0.y); v += w1 * unpk2(c1.y); v += w2 * unpk2(c2.y); v += w3 * unpk2(c3.y);
      pk.y = cvt_pk_bf16(v[0], v[1]); }
    { floatx2 v = w0 * unpk2(c0.z); v += w1 * unpk2(c1.z); v += w2 * unpk2(c2.z); v += w3 * unpk2(c3.z);
      pk.z = cvt_pk_bf16(v[0], v[1]); }
    { floatx2 v = w0 * unpk2(c0.w); v += w1 * unpk2(c1.w); v += w2 * unpk2(c2.w); v += w3 * unpk2(c3.w);
      pk.w = cvt_pk_bf16(v[0], v[1]); }
    return pk;
}

// ---------------------------------------------------------------------------
// NCHW f32 -> NHWC bf16 transpose via LDS tile
__global__ __launch_bounds__(256) void k_transpose(const float* __restrict__ x,
                                                   unsigned short* __restrict__ xt) {
    __shared__ float tile[64 * 65];
    int bb  = blockIdx.x / 144;
    int sp0 = (blockIdx.x % 144) * 64;
    int t = threadIdx.x;
    int s = t & 63, cg = t >> 6;
    #pragma unroll
    for (int i = 0; i < 16; ++i) {
        int c = cg * 16 + i;
        tile[c * 65 + s] = x[(size_t)(bb * 64 + c) * HW_ + sp0 + s];
    }
    __syncthreads();
    // each lane packs 8 channels of one pixel -> 1KB contiguous per wave-store
    int c8 = t & 7, sgrp = t >> 3;      // sgrp 0..31
    #pragma unroll
    for (int i = 0; i < 2; ++i) {
        int s2 = i * 32 + sgrp;
        unsigned v[8];
        #pragma unroll
        for (int j = 0; j < 8; ++j)
            v[j] = f2bf(tile[(c8 * 8 + j) * 65 + s2]);
        uint4 pk;
        pk.x = v[0] | (v[1] << 16); pk.y = v[2] | (v[3] << 16);
        pk.z = v[4] | (v[5] << 16); pk.w = v[6] | (v[7] << 16);
        *(uint4*)(xt + (size_t)(bb * HW_ + sp0 + s2) * 64 + c8 * 8) = pk;
    }
}

// ---------------------------------------------------------------------------
// Pack weights into MFMA A-fragment order (k = tap*64 + c).
__global__ __launch_bounds__(256) void k_prepw(const float* __restrict__ offw,
                                               const float* __restrict__ mw,
                                               const float* __restrict__ convw,
                                               unsigned short* __restrict__ wfm,
                                               unsigned short* __restrict__ wfo) {
    int g = blockIdx.x * 256 + threadIdx.x;
    if (g < 4608) {
        int lane = g & 63, mtks = g >> 6;
        int mt = mtks & 3, ks = mtks >> 2;
        int o = mt * 16 + (lane & 15), quad = lane >> 4;
        unsigned v[8];
        #pragma unroll
        for (int j = 0; j < 8; ++j) {
            int k = ks * 32 + quad * 8 + j;
            int t = k / 64, c = k % 64;
            v[j] = f2bf(convw[(size_t)(o * 64 + c) * 9 + t]);
        }
        uint4 pk;
        pk.x = v[0] | (v[1] << 16); pk.y = v[2] | (v[3] << 16);
        pk.z = v[4] | (v[5] << 16); pk.w = v[6] | (v[7] << 16);
        *(uint4*)(wfm + (size_t)g * 8) = pk;
    } else if (g < 4608 + 2304) {
        int g2 = g - 4608;
        int lane = g2 & 63, mtks = g2 >> 6;
        int mt = mtks & 1, ks = mtks >> 1;
        int m = mt * 16 + (lane & 15), quad = lane >> 4;
        unsigned v[8];
        #pragma unroll
        for (int j = 0; j < 8; ++j) {
            int k = ks * 32 + quad * 8 + j;
            int t = k / 64, c = k % 64;
            float f = 0.f;
            if (m < 18)      f = offw[(size_t)(m * 64 + c) * 9 + t];
            else if (m < 27) f = mw[(size_t)((m - 18) * 64 + c) * 9 + t];
            v[j] = f2bf(f);
        }
        uint4 pk;
        pk.x = v[0] | (v[1] << 16); pk.y = v[2] | (v[3] << 16);
        pk.z = v[4] | (v[5] << 16); pk.w = v[6] | (v[7] << 16);
        *(uint4*)(wfo + (size_t)g2 * 8) = pk;
    }
}

// ---------------------------------------------------------------------------
// Fused kernel. Block = 256 thr = 4 waves, owns 64 px (2 rows x 32 cols).
// x window staged in LDS (swizzled); wfm A-frags persistent in VGPRs
// (wave = 2 of 4 o-tiles x 32 px). All phase-3 gathers are ds_read.
__global__ __launch_bounds__(256, 2) void k_fused(const unsigned short* __restrict__ xt,
                                                  const unsigned short* __restrict__ wfo,
                                                  const unsigned short* __restrict__ wfm,
                                                  const float* __restrict__ offb,
                                                  const float* __restrict__ mb,
                                                  const float* __restrict__ convb,
                                                  float* __restrict__ out) {
    __shared__ __align__(16) unsigned char s_win[(WINPX + NSLOTS) * 128];  // 48128 B
    __shared__ float s_off[27 * 66];                                       // 7128 B
    __shared__ __align__(16) unsigned char s_meta[64 * 9 * 16];            // 9216 B
    __shared__ int s_cnt;

    int tid = threadIdx.x;
    int w = tid >> 6, lane = tid & 63, col = lane & 15, quad = lane >> 4;
    int blk = blockIdx.x;
    int bb  = blk / 144;
    int rem = blk % 144;
    int hr  = (rem / 3) * 2;            // top row of the 2-row tile
    int wc  = (rem % 3) * 32;           // left col of the 32-col segment
    const unsigned short* xtb = xt + (size_t)bb * HW_ * 64;

    // ---- stage window: rows hr-3..hr+5, cols wc-4..wc+35, chunk-swizzled ----
    if (tid == 0) s_cnt = 0;
    #pragma unroll
    for (int i = 0; i < 12; ++i) {
        int cid = i * 256 + tid;
        if (cid < WINPX * 8) {
            int p = cid >> 3, ch = cid & 7;
            int wr = p / NWC, wcl = p % NWC;
            int gr = hr - 3 + wr, gc = wc - 4 + wcl;
            uint4 v = make_uint4(0, 0, 0, 0);
            if ((unsigned)gr < 96u && (unsigned)gc < 96u)
                v = *(const uint4*)(xtb + (size_t)(gr * 96 + gc) * 64 + ch * 8);
            *(uint4*)(s_win + (size_t)p * 128 + ((ch ^ (p & 7)) * 16)) = v;
        }
    }
    __syncthreads();

    // ---- phase 1: offset/mod conv GEMM (B from LDS window) ----
    // wave w: 16 px at (row hr + (w>>1), cols wc + (w&1)*16 + col)
    floatx4 aoff0 = (floatx4){0.f, 0.f, 0.f, 0.f};
    floatx4 aoff1 = (floatx4){0.f, 0.f, 0.f, 0.f};
    {
        int wr_base = 3 + (w >> 1);
        int wc_base = 4 + (w & 1) * 16 + col;
        #pragma unroll
        for (int t = 0; t < 9; ++t) {
            int dh = t / 3 - 1, dw = t % 3 - 1;
            int p = (wr_base + dh) * NWC + (wc_base + dw);
            int pb = p << 7, psw = (p & 7) << 4;
            #pragma unroll
            for (int ksl = 0; ksl < 2; ++ksl) {
                int ks = t * 2 + ksl;
                bf16x8 a0 = *(const bf16x8*)(wfo + ((size_t)(ks * 2 + 0) * 64 + lane) * 8);
                bf16x8 a1 = *(const bf16x8*)(wfo + ((size_t)(ks * 2 + 1) * 64 + lane) * 8);
                uint4 bvu = *(const uint4*)(s_win + pb + ((quad * 16 + ksl * 64) ^ psw));
                union { uint4 u; bf16x8 bv; } ub; ub.u = bvu;
                aoff0 = __builtin_amdgcn_mfma_f32_16x16x32_bf16(a0, ub.bv, aoff0, 0, 0, 0);
                aoff1 = __builtin_amdgcn_mfma_f32_16x16x32_bf16(a1, ub.bv, aoff1, 0, 0, 0);
            }
        }
    }
    #pragma unroll
    for (int r = 0; r < 4; ++r) {
        s_off[(quad * 4 + r) * 66 + (w * 16 + col)] = aoff0[r];
        int m = 16 + quad * 4 + r;
        if (m < 27) s_off[m * 66 + (w * 16 + col)] = aoff1[r];
    }
    __syncthreads();

    // ---- phase 2: bilinear metadata for 64 px x 9 n; LDS-window indices ----
    for (int id = tid; id < 576; id += 256) {
        int px = id & 63, n = id >> 6;
        float ox = s_off[n * 66 + px]        + offb[n];
        float oy = s_off[(9 + n) * 66 + px]  + offb[9 + n];
        float mv = s_off[(18 + n) * 66 + px] + mb[n];
        float modv = 1.f / (1.f + __expf(-mv));
        int prow = hr + (px >> 5), pcol = wc + (px & 31);
        float pxx = ox + (float)(prow + 1) + (float)(n / 3 - 1);
        float pyy = oy + (float)(pcol + 1) + (float)(n % 3 - 1);
        float flx = floorf(pxx), fly = floorf(pyy);
        float tlxf = fminf(fmaxf(flx,       0.f), 97.f);
        float tlyf = fminf(fmaxf(fly,       0.f), 97.f);
        float brxf = fminf(fmaxf(flx + 1.f, 0.f), 97.f);
        float bryf = fminf(fmaxf(fly + 1.f, 0.f), 97.f);
        float pcx  = fminf(fmaxf(pxx, 0.f), 97.f);
        float pcy  = fminf(fmaxf(pyy, 0.f), 97.f);
        float gx0 = 1.f + tlxf - pcx;
        float gx1 = 1.f - (brxf - pcx);
        float gy0 = 1.f + tlyf - pcy;
        float gy1 = 1.f - (bryf - pcy);
        int tlx = (int)tlxf, tly = (int)tlyf, brx = (int)brxf, bry = (int)bryf;
        int   qxs[4] = {tlx, tlx, brx, brx};
        int   qys[4] = {tly, bry, tly, bry};
        float gs4[4] = {gx0 * gy0, gx0 * gy1, gx1 * gy0, gx1 * gy1};
        unsigned short si[4]; unsigned short hg[4];
        #pragma unroll
        for (int c4 = 0; c4 < 4; ++c4) {
            int qx = qxs[c4], qy = qys[c4];
            bool valid = (qx >= 1) && (qx <= 96) && (qy >= 1) && (qy <= 96);
            int gr = qx - 1, gc = qy - 1;
            int wr = gr - (hr - 3), wcl = gc - (wc - 4);
            bool inwin = ((unsigned)wr < (unsigned)NWR) && ((unsigned)wcl < (unsigned)NWC);
            unsigned short idxv; float gvf;
            if (inwin) {
                idxv = (unsigned short)(wr * NWC + wcl);   // zeros staged for out-of-image
                gvf = gs4[c4] * modv;
            } else if (!valid) {
                idxv = 0; gvf = 0.f;
            } else {
                // rare: valid corner outside window -> copy into LDS overflow slot
                int s = atomicAdd(&s_cnt, 1);
                int gidx = gr * 96 + gc;
                if (s < NSLOTS) {
                    int ps = WINPX + s;
                    #pragma unroll
                    for (int ch = 0; ch < 8; ++ch) {
                        uint4 v = *(const uint4*)(xtb + (size_t)gidx * 64 + ch * 8);
                        *(uint4*)(s_win + (size_t)ps * 128 + ((ch ^ (ps & 7)) * 16)) = v;
                    }
                    idxv = (unsigned short)ps;
                } else {
                    idxv = (unsigned short)(0x8000u | (unsigned)gidx);  // global fallback tag
                }
                gvf = gs4[c4] * modv;
            }
            si[c4] = idxv;
            hg[c4] = __half_as_ushort(__float2half_rn(gvf));
        }
        uint4 mw4;
        mw4.x = si[0] | ((unsigned)si[1] << 16);
        mw4.y = si[2] | ((unsigned)si[3] << 16);
        mw4.z = hg[0] | ((unsigned)hg[1] << 16);
        mw4.w = hg[2] | ((unsigned)hg[3] << 16);
        *(uint4*)(s_meta + ((size_t)px * 9 + n) * 16) = mw4;
    }
    __syncthreads();

    // ---- phase 3: main contraction; A-frags persistent in VGPRs ----
    int mth = w & 1, pg = w >> 1;      // wave: o-half mth, px-half pg
    bf16x8 af[18][2];
    #pragma unroll
    for (int ks = 0; ks < 18; ++ks)
        #pragma unroll
        for (int mtl = 0; mtl < 2; ++mtl)
            af[ks][mtl] = *(const bf16x8*)(wfm + ((size_t)(ks * 4 + mth * 2 + mtl) * 64 + lane) * 8);

    floatx4 acc[2][2];
    #pragma unroll
    for (int jj = 0; jj < 2; ++jj)
        #pragma unroll
        for (int mtl = 0; mtl < 2; ++mtl) acc[jj][mtl] = (floatx4){0.f, 0.f, 0.f, 0.f};

    int qk0 = quad * 16, qk1 = quad * 16 + 64;

    #pragma unroll
    for (int n = 0; n < 9; ++n) {
        #pragma unroll
        for (int jj = 0; jj < 2; ++jj) {
            int px = pg * 32 + jj * 16 + col;
            uint4 mu = *(const uint4*)(s_meta + ((size_t)px * 9 + n) * 16);
            unsigned i0 = mu.x & 0xFFFFu, i1 = mu.x >> 16;
            unsigned i2 = mu.y & 0xFFFFu, i3 = mu.y >> 16;
            int pm0 = (i0 & 0x8000u) ? 0 : (int)i0;
            int pm1 = (i1 & 0x8000u) ? 0 : (int)i1;
            int pm2 = (i2 & 0x8000u) ? 0 : (int)i2;
            int pm3 = (i3 & 0x8000u) ? 0 : (int)i3;
            int b0 = pm0 << 7, s0 = (pm0 & 7) << 4;
            int b1 = pm1 << 7, s1 = (pm1 & 7) << 4;
            int b2 = pm2 << 7, s2 = (pm2 & 7) << 4;
            int b3 = pm3 << 7, s3 = (pm3 & 7) << 4;
            uint4 cA0 = *(const uint4*)(s_win + b0 + (qk0 ^ s0));
            uint4 cA1 = *(const uint4*)(s_win + b1 + (qk0 ^ s1));
            uint4 cA2 = *(const uint4*)(s_win + b2 + (qk0 ^ s2));
            uint4 cA3 = *(const uint4*)(s_win + b3 + (qk0 ^ s3));
            uint4 cB0 = *(const uint4*)(s_win + b0 + (qk1 ^ s0));
            uint4 cB1 = *(const uint4*)(s_win + b1 + (qk1 ^ s1));
            uint4 cB2 = *(const uint4*)(s_win + b2 + (qk1 ^ s2));
            uint4 cB3 = *(const uint4*)(s_win + b3 + (qk1 ^ s3));
            if (__any((int)((i0 | i1 | i2 | i3) & 0x8000u))) {
                // ultra-rare global fallback (slot overflow)
                if (i0 & 0x8000u) { size_t ga = (size_t)(i0 & 0x3FFFu) * 64 + quad * 8;
                    cA0 = *(const uint4*)(xtb + ga); cB0 = *(const uint4*)(xtb + ga + 32); }
                if (i1 & 0x8000u) { size_t ga = (size_t)(i1 & 0x3FFFu) * 64 + quad * 8;
                    cA1 = *(const uint4*)(xtb + ga); cB1 = *(const uint4*)(xtb + ga + 32); }
                if (i2 & 0x8000u) { size_t ga = (size_t)(i2 & 0x3FFFu) * 64 + quad * 8;
                    cA2 = *(const uint4*)(xtb + ga); cB2 = *(const uint4*)(xtb + ga + 32); }
                if (i3 & 0x8000u) { size_t ga = (size_t)(i3 & 0x3FFFu) * 64 + quad * 8;
                    cA3 = *(const uint4*)(xtb + ga); cB3 = *(const uint4*)(xtb + ga + 32); }
            }
            float g0 = __half2float(__ushort_as_half((unsigned short)(mu.z & 0xFFFFu)));
            float g1 = __half2float(__ushort_as_half((unsigned short)(mu.z >> 16)));
            float g2 = __half2float(__ushort_as_half((unsigned short)(mu.w & 0xFFFFu)));
            float g3 = __half2float(__ushort_as_half((unsigned short)(mu.w >> 16)));
            floatx2 w0 = {g0, g0}, w1 = {g1, g1}, w2 = {g2, g2}, w3 = {g3, g3};
            uint4 pA = combine4(cA0, cA1, cA2, cA3, w0, w1, w2, w3);
            uint4 pB = combine4(cB0, cB1, cB2, cB3, w0, w1, w2, w3);
            union { uint4 u; bf16x8 bv; } uA, uB; uA.u = pA; uB.u = pB;
            acc[jj][0] = __builtin_amdgcn_mfma_f32_16x16x32_bf16(af[n * 2 + 0][0], uA.bv, acc[jj][0], 0, 0, 0);
            acc[jj][1] = __builtin_amdgcn_mfma_f32_16x16x32_bf16(af[n * 2 + 0][1], uA.bv, acc[jj][1], 0, 0, 0);
            acc[jj][0] = __builtin_amdgcn_mfma_f32_16x16x32_bf16(af[n * 2 + 1][0], uB.bv, acc[jj][0], 0, 0, 0);
            acc[jj][1] = __builtin_amdgcn_mfma_f32_16x16x32_bf16(af[n * 2 + 1][1], uB.bv, acc[jj][1], 0, 0, 0);
        }
    }

    // ---- epilogue ----
    int prow = hr + pg;
    #pragma unroll
    for (int mtl = 0; mtl < 2; ++mtl) {
        float4 cb4 = *(const float4*)&convb[mth * 32 + mtl * 16 + quad * 4];
        #pragma unroll
        for (int jj = 0; jj < 2; ++jj) {
            int sp = prow * 96 + wc + jj * 16 + col;
            #pragma unroll
            for (int r = 0; r < 4; ++r) {
                int o = mth * 32 + mtl * 16 + quad * 4 + r;
                float bias = (r == 0) ? cb4.x : (r == 1) ? cb4.y : (r == 2) ? cb4.z : cb4.w;
                out[(size_t)(bb * 64 + o) * HW_ + sp] = acc[jj][mtl][r] + bias;
            }
        }
    }
}

// ---------------------------------------------------------------------------
extern "C" void kernel_launch(void* const* d_in, const int* in_sizes, int n_in,
                              void* d_out, int out_size, void* d_ws, size_t ws_size,
                              hipStream_t stream) {
    const float* x     = (const float*)d_in[0];
    const float* offw  = (const float*)d_in[1];
    const float* offb  = (const float*)d_in[2];
    const float* mw    = (const float*)d_in[3];
    const float* mb    = (const float*)d_in[4];
    const float* convw = (const float*)d_in[5];
    const float* convb = (const float*)d_in[6];
    char* ws = (char*)d_ws;
    unsigned short* xt16 = (unsigned short*)(ws + XT_OFF);
    unsigned short* wfm  = (unsigned short*)(ws + WFM_OFF);
    unsigned short* wfo  = (unsigned short*)(ws + WFO_OFF);
    float* out = (float*)d_out;

    k_transpose<<<dim3(1152), dim3(256), 0, stream>>>(x, xt16);
    k_prepw    <<<dim3(27),   dim3(256), 0, stream>>>(offw, mw, convw, wfm, wfo);
    k_fused    <<<dim3(1152), dim3(256), 0, stream>>>(xt16, wfo, wfm, offb, mb, convb, out);
}

// Round 4
// 126.074 us; speedup vs baseline: 1.1999x; 1.0781x over previous
//
#include <hip/hip_runtime.h>
#include <hip/hip_fp16.h>
#include <cstddef>

#define B_   8
#define H_   96
#define W_   96
#define HW_  9216
#define PIX_ 73728

// LDS window geometry: rows hr-3..hr+5 (9), cols wc-4..wc+35 (40)
#define NWR    9
#define NWC    40
#define WINPX  360
#define NSLOTS 16

typedef __attribute__((ext_vector_type(8))) _Float16 halfx8;
typedef __attribute__((ext_vector_type(2))) __fp16 fp16x2_raw;
typedef __attribute__((ext_vector_type(4))) float floatx4;

// ws layout (byte offsets)
#define XT_OFF   0                          // fp16 NHWC x: PIX*64*2
#define WFM_OFF  (XT_OFF + PIX_*64*2)       // main W frags: 18*4*64*8 fp16
#define WFO_OFF  (WFM_OFF + 18*4*64*8*2)    // offs W frags: 18*2*64*8 fp16

__device__ __forceinline__ unsigned pk2h(float a, float b) {
    fp16x2_raw h = __builtin_amdgcn_cvt_pkrtz(a, b);
    union { fp16x2_raw h2; unsigned u; } t; t.h2 = h; return t.u;
}
__device__ __forceinline__ halfx8 uph8(uint4 u) {
    union { uint4 u4; halfx8 h; } t; t.u4 = u; return t.h;
}
__device__ __forceinline__ halfx8 splat8(unsigned d) {
    union { unsigned u[4]; halfx8 h; } t;
    t.u[0] = d; t.u[1] = d; t.u[2] = d; t.u[3] = d; return t.h;
}

// ---------------------------------------------------------------------------
// NCHW f32 -> NHWC fp16 transpose via LDS tile
__global__ __launch_bounds__(256) void k_transpose(const float* __restrict__ x,
                                                   unsigned short* __restrict__ xt) {
    __shared__ float tile[64 * 65];
    int bb  = blockIdx.x / 144;
    int sp0 = (blockIdx.x % 144) * 64;
    int t = threadIdx.x;
    int s = t & 63, cg = t >> 6;
    #pragma unroll
    for (int i = 0; i < 16; ++i) {
        int c = cg * 16 + i;
        tile[c * 65 + s] = x[(size_t)(bb * 64 + c) * HW_ + sp0 + s];
    }
    __syncthreads();
    // each lane packs 8 channels of one pixel -> 1KB contiguous per wave-store
    int c8 = t & 7, sgrp = t >> 3;      // sgrp 0..31
    #pragma unroll
    for (int i = 0; i < 2; ++i) {
        int s2 = i * 32 + sgrp;
        uint4 pk;
        pk.x = pk2h(tile[(c8 * 8 + 0) * 65 + s2], tile[(c8 * 8 + 1) * 65 + s2]);
        pk.y = pk2h(tile[(c8 * 8 + 2) * 65 + s2], tile[(c8 * 8 + 3) * 65 + s2]);
        pk.z = pk2h(tile[(c8 * 8 + 4) * 65 + s2], tile[(c8 * 8 + 5) * 65 + s2]);
        pk.w = pk2h(tile[(c8 * 8 + 6) * 65 + s2], tile[(c8 * 8 + 7) * 65 + s2]);
        *(uint4*)(xt + (size_t)(bb * HW_ + sp0 + s2) * 64 + c8 * 8) = pk;
    }
}

// ---------------------------------------------------------------------------
// Pack weights into MFMA A-fragment order (k = tap*64 + c), fp16.
__global__ __launch_bounds__(256) void k_prepw(const float* __restrict__ offw,
                                               const float* __restrict__ mw,
                                               const float* __restrict__ convw,
                                               unsigned short* __restrict__ wfm,
                                               unsigned short* __restrict__ wfo) {
    int g = blockIdx.x * 256 + threadIdx.x;
    if (g < 4608) {
        int lane = g & 63, mtks = g >> 6;
        int mt = mtks & 3, ks = mtks >> 2;
        int o = mt * 16 + (lane & 15), quad = lane >> 4;
        float v[8];
        #pragma unroll
        for (int j = 0; j < 8; ++j) {
            int k = ks * 32 + quad * 8 + j;
            int t = k / 64, c = k % 64;
            v[j] = convw[(size_t)(o * 64 + c) * 9 + t];
        }
        uint4 pk;
        pk.x = pk2h(v[0], v[1]); pk.y = pk2h(v[2], v[3]);
        pk.z = pk2h(v[4], v[5]); pk.w = pk2h(v[6], v[7]);
        *(uint4*)(wfm + (size_t)g * 8) = pk;
    } else if (g < 4608 + 2304) {
        int g2 = g - 4608;
        int lane = g2 & 63, mtks = g2 >> 6;
        int mt = mtks & 1, ks = mtks >> 1;
        int m = mt * 16 + (lane & 15), quad = lane >> 4;
        float v[8];
        #pragma unroll
        for (int j = 0; j < 8; ++j) {
            int k = ks * 32 + quad * 8 + j;
            int t = k / 64, c = k % 64;
            float f = 0.f;
            if (m < 18)      f = offw[(size_t)(m * 64 + c) * 9 + t];
            else if (m < 27) f = mw[(size_t)((m - 18) * 64 + c) * 9 + t];
            v[j] = f;
        }
        uint4 pk;
        pk.x = pk2h(v[0], v[1]); pk.y = pk2h(v[2], v[3]);
        pk.z = pk2h(v[4], v[5]); pk.w = pk2h(v[6], v[7]);
        *(uint4*)(wfo + (size_t)g2 * 8) = pk;
    }
}

// ---------------------------------------------------------------------------
// Fused kernel. Block = 256 thr = 4 waves, owns 64 px (2 rows x 32 cols).
// x window staged in LDS (swizzled, fp16); phase-3 combine in packed fp16.
__global__ __launch_bounds__(256, 2) void k_fused(const unsigned short* __restrict__ xt,
                                                  const unsigned short* __restrict__ wfo,
                                                  const unsigned short* __restrict__ wfm,
                                                  const float* __restrict__ offb,
                                                  const float* __restrict__ mb,
                                                  const float* __restrict__ convb,
                                                  float* __restrict__ out) {
    __shared__ __align__(16) unsigned char s_win[(WINPX + NSLOTS) * 128];  // 48128 B
    __shared__ float s_off[27 * 66];                                       // 7128 B
    __shared__ __align__(16) unsigned char s_meta[64 * 9 * 16];            // 9216 B
    __shared__ int s_cnt;

    int tid = threadIdx.x;
    int w = tid >> 6, lane = tid & 63, col = lane & 15, quad = lane >> 4;
    int blk = blockIdx.x;
    int bb  = blk / 144;
    int rem = blk % 144;
    int hr  = (rem / 3) * 2;            // top row of the 2-row tile
    int wc  = (rem % 3) * 32;           // left col of the 32-col segment
    const unsigned short* xtb = xt + (size_t)bb * HW_ * 64;

    // ---- stage window: rows hr-3..hr+5, cols wc-4..wc+35, chunk-swizzled ----
    if (tid == 0) s_cnt = 0;
    #pragma unroll
    for (int i = 0; i < 12; ++i) {
        int cid = i * 256 + tid;
        if (cid < WINPX * 8) {
            int p = cid >> 3, ch = cid & 7;
            int wr = p / NWC, wcl = p % NWC;
            int gr = hr - 3 + wr, gc = wc - 4 + wcl;
            uint4 v = make_uint4(0, 0, 0, 0);
            if ((unsigned)gr < 96u && (unsigned)gc < 96u)
                v = *(const uint4*)(xtb + (size_t)(gr * 96 + gc) * 64 + ch * 8);
            *(uint4*)(s_win + (size_t)p * 128 + ((ch ^ (p & 7)) * 16)) = v;
        }
    }
    __syncthreads();

    // ---- phase 1: offset/mod conv GEMM (B from LDS window) ----
    floatx4 aoff0 = (floatx4){0.f, 0.f, 0.f, 0.f};
    floatx4 aoff1 = (floatx4){0.f, 0.f, 0.f, 0.f};
    {
        int wr_base = 3 + (w >> 1);
        int wc_base = 4 + (w & 1) * 16 + col;
        #pragma unroll
        for (int t = 0; t < 9; ++t) {
            int dh = t / 3 - 1, dw = t % 3 - 1;
            int p = (wr_base + dh) * NWC + (wc_base + dw);
            int pb = p << 7, psw = (p & 7) << 4;
            #pragma unroll
            for (int ksl = 0; ksl < 2; ++ksl) {
                int ks = t * 2 + ksl;
                halfx8 a0 = *(const halfx8*)(wfo + ((size_t)(ks * 2 + 0) * 64 + lane) * 8);
                halfx8 a1 = *(const halfx8*)(wfo + ((size_t)(ks * 2 + 1) * 64 + lane) * 8);
                uint4 bvu = *(const uint4*)(s_win + pb + ((quad * 16 + ksl * 64) ^ psw));
                halfx8 bv = uph8(bvu);
                aoff0 = __builtin_amdgcn_mfma_f32_16x16x32_f16(a0, bv, aoff0, 0, 0, 0);
                aoff1 = __builtin_amdgcn_mfma_f32_16x16x32_f16(a1, bv, aoff1, 0, 0, 0);
            }
        }
    }
    #pragma unroll
    for (int r = 0; r < 4; ++r) {
        s_off[(quad * 4 + r) * 66 + (w * 16 + col)] = aoff0[r];
        int m = 16 + quad * 4 + r;
        if (m < 27) s_off[m * 66 + (w * 16 + col)] = aoff1[r];
    }
    __syncthreads();

    // ---- phase 2: bilinear metadata for 64 px x 9 n; LDS-window indices ----
    for (int id = tid; id < 576; id += 256) {
        int px = id & 63, n = id >> 6;
        float ox = s_off[n * 66 + px]        + offb[n];
        float oy = s_off[(9 + n) * 66 + px]  + offb[9 + n];
        float mv = s_off[(18 + n) * 66 + px] + mb[n];
        float modv = 1.f / (1.f + __expf(-mv));
        int prow = hr + (px >> 5), pcol = wc + (px & 31);
        float pxx = ox + (float)(prow + 1) + (float)(n / 3 - 1);
        float pyy = oy + (float)(pcol + 1) + (float)(n % 3 - 1);
        float flx = floorf(pxx), fly = floorf(pyy);
        float tlxf = fminf(fmaxf(flx,       0.f), 97.f);
        float tlyf = fminf(fmaxf(fly,       0.f), 97.f);
        float brxf = fminf(fmaxf(flx + 1.f, 0.f), 97.f);
        float bryf = fminf(fmaxf(fly + 1.f, 0.f), 97.f);
        float pcx  = fminf(fmaxf(pxx, 0.f), 97.f);
        float pcy  = fminf(fmaxf(pyy, 0.f), 97.f);
        float gx0 = 1.f + tlxf - pcx;
        float gx1 = 1.f - (brxf - pcx);
        float gy0 = 1.f + tlyf - pcy;
        float gy1 = 1.f - (bryf - pcy);
        int tlx = (int)tlxf, tly = (int)tlyf, brx = (int)brxf, bry = (int)bryf;
        int   qxs[4] = {tlx, tlx, brx, brx};
        int   qys[4] = {tly, bry, tly, bry};
        float gs4[4] = {gx0 * gy0, gx0 * gy1, gx1 * gy0, gx1 * gy1};
        unsigned short si[4]; unsigned short hg[4];
        #pragma unroll
        for (int c4 = 0; c4 < 4; ++c4) {
            int qx = qxs[c4], qy = qys[c4];
            bool valid = (qx >= 1) && (qx <= 96) && (qy >= 1) && (qy <= 96);
            int gr = qx - 1, gc = qy - 1;
            int wr = gr - (hr - 3), wcl = gc - (wc - 4);
            bool inwin = ((unsigned)wr < (unsigned)NWR) && ((unsigned)wcl < (unsigned)NWC);
            unsigned short idxv; float gvf;
            if (inwin) {
                idxv = (unsigned short)(wr * NWC + wcl);   // zeros staged for out-of-image
                gvf = gs4[c4] * modv;
            } else if (!valid) {
                idxv = 0; gvf = 0.f;
            } else {
                // rare: valid corner outside window -> copy into LDS overflow slot
                int s = atomicAdd(&s_cnt, 1);
                int gidx = gr * 96 + gc;
                if (s < NSLOTS) {
                    int ps = WINPX + s;
                    #pragma unroll
                    for (int ch = 0; ch < 8; ++ch) {
                        uint4 v = *(const uint4*)(xtb + (size_t)gidx * 64 + ch * 8);
                        *(uint4*)(s_win + (size_t)ps * 128 + ((ch ^ (ps & 7)) * 16)) = v;
                    }
                    idxv = (unsigned short)ps;
                } else {
                    idxv = (unsigned short)(0x8000u | (unsigned)gidx);  // global fallback tag
                }
                gvf = gs4[c4] * modv;
            }
            si[c4] = idxv;
            hg[c4] = __half_as_ushort(__float2half_rn(gvf));
        }
        uint4 mw4;
        mw4.x = si[0] | ((unsigned)si[1] << 16);
        mw4.y = si[2] | ((unsigned)si[3] << 16);
        mw4.z = hg[0] | ((unsigned)hg[1] << 16);
        mw4.w = hg[2] | ((unsigned)hg[3] << 16);
        *(uint4*)(s_meta + ((size_t)px * 9 + n) * 16) = mw4;
    }
    __syncthreads();

    // ---- phase 3: main contraction; packed-fp16 combine ----
    int mth = w & 1, pg = w >> 1;      // wave: o-half mth, px-half pg
    floatx4 acc[2][2];
    #pragma unroll
    for (int jj = 0; jj < 2; ++jj)
        #pragma unroll
        for (int mtl = 0; mtl < 2; ++mtl) acc[jj][mtl] = (floatx4){0.f, 0.f, 0.f, 0.f};

    int qk0 = quad * 16, qk1 = quad * 16 + 64;

    #pragma unroll
    for (int n = 0; n < 9; ++n) {
        halfx8 af00 = *(const halfx8*)(wfm + ((size_t)((n * 2 + 0) * 4 + mth * 2 + 0) * 64 + lane) * 8);
        halfx8 af01 = *(const halfx8*)(wfm + ((size_t)((n * 2 + 0) * 4 + mth * 2 + 1) * 64 + lane) * 8);
        halfx8 af10 = *(const halfx8*)(wfm + ((size_t)((n * 2 + 1) * 4 + mth * 2 + 0) * 64 + lane) * 8);
        halfx8 af11 = *(const halfx8*)(wfm + ((size_t)((n * 2 + 1) * 4 + mth * 2 + 1) * 64 + lane) * 8);
        #pragma unroll
        for (int jj = 0; jj < 2; ++jj) {
            int px = pg * 32 + jj * 16 + col;
            uint4 mu = *(const uint4*)(s_meta + ((size_t)px * 9 + n) * 16);
            unsigned i0 = mu.x & 0xFFFFu, i1 = mu.x >> 16;
            unsigned i2 = mu.y & 0xFFFFu, i3 = mu.y >> 16;
            int pm0 = (i0 & 0x8000u) ? 0 : (int)i0;
            int pm1 = (i1 & 0x8000u) ? 0 : (int)i1;
            int pm2 = (i2 & 0x8000u) ? 0 : (int)i2;
            int pm3 = (i3 & 0x8000u) ? 0 : (int)i3;
            int b0 = pm0 << 7, s0 = (pm0 & 7) << 4;
            int b1 = pm1 << 7, s1 = (pm1 & 7) << 4;
            int b2 = pm2 << 7, s2 = (pm2 & 7) << 4;
            int b3 = pm3 << 7, s3 = (pm3 & 7) << 4;
            uint4 cA0 = *(const uint4*)(s_win + b0 + (qk0 ^ s0));
            uint4 cA1 = *(const uint4*)(s_win + b1 + (qk0 ^ s1));
            uint4 cA2 = *(const uint4*)(s_win + b2 + (qk0 ^ s2));
            uint4 cA3 = *(const uint4*)(s_win + b3 + (qk0 ^ s3));
            uint4 cB0 = *(const uint4*)(s_win + b0 + (qk1 ^ s0));
            uint4 cB1 = *(const uint4*)(s_win + b1 + (qk1 ^ s1));
            uint4 cB2 = *(const uint4*)(s_win + b2 + (qk1 ^ s2));
            uint4 cB3 = *(const uint4*)(s_win + b3 + (qk1 ^ s3));
            if (__any((int)((i0 | i1 | i2 | i3) & 0x8000u))) {
                // ultra-rare global fallback (slot overflow)
                if (i0 & 0x8000u) { size_t ga = (size_t)(i0 & 0x3FFFu) * 64 + quad * 8;
                    cA0 = *(const uint4*)(xtb + ga); cB0 = *(const uint4*)(xtb + ga + 32); }
                if (i1 & 0x8000u) { size_t ga = (size_t)(i1 & 0x3FFFu) * 64 + quad * 8;
                    cA1 = *(const uint4*)(xtb + ga); cB1 = *(const uint4*)(xtb + ga + 32); }
                if (i2 & 0x8000u) { size_t ga = (size_t)(i2 & 0x3FFFu) * 64 + quad * 8;
                    cA2 = *(const uint4*)(xtb + ga); cB2 = *(const uint4*)(xtb + ga + 32); }
                if (i3 & 0x8000u) { size_t ga = (size_t)(i3 & 0x3FFFu) * 64 + quad * 8;
                    cA3 = *(const uint4*)(xtb + ga); cB3 = *(const uint4*)(xtb + ga + 32); }
            }
            // splat each half g to a packed pair, then pure v_pk_mul/fma_f16
            unsigned gl0 = (mu.z & 0xFFFFu) | (mu.z << 16);
            unsigned gl1 = (mu.z >> 16) | (mu.z & 0xFFFF0000u);
            unsigned gl2 = (mu.w & 0xFFFFu) | (mu.w << 16);
            unsigned gl3 = (mu.w >> 16) | (mu.w & 0xFFFF0000u);
            halfx8 g0 = splat8(gl0), g1 = splat8(gl1), g2 = splat8(gl2), g3 = splat8(gl3);
            halfx8 vA = uph8(cA0) * g0;
            vA += uph8(cA1) * g1; vA += uph8(cA2) * g2; vA += uph8(cA3) * g3;
            halfx8 vB = uph8(cB0) * g0;
            vB += uph8(cB1) * g1; vB += uph8(cB2) * g2; vB += uph8(cB3) * g3;
            acc[jj][0] = __builtin_amdgcn_mfma_f32_16x16x32_f16(af00, vA, acc[jj][0], 0, 0, 0);
            acc[jj][1] = __builtin_amdgcn_mfma_f32_16x16x32_f16(af01, vA, acc[jj][1], 0, 0, 0);
            acc[jj][0] = __builtin_amdgcn_mfma_f32_16x16x32_f16(af10, vB, acc[jj][0], 0, 0, 0);
            acc[jj][1] = __builtin_amdgcn_mfma_f32_16x16x32_f16(af11, vB, acc[jj][1], 0, 0, 0);
        }
    }

    // ---- epilogue ----
    int prow = hr + pg;
    #pragma unroll
    for (int mtl = 0; mtl < 2; ++mtl) {
        float4 cb4 = *(const float4*)&convb[mth * 32 + mtl * 16 + quad * 4];
        #pragma unroll
        for (int jj = 0; jj < 2; ++jj) {
            int sp = prow * 96 + wc + jj * 16 + col;
            #pragma unroll
            for (int r = 0; r < 4; ++r) {
                int o = mth * 32 + mtl * 16 + quad * 4 + r;
                float bias = (r == 0) ? cb4.x : (r == 1) ? cb4.y : (r == 2) ? cb4.z : cb4.w;
                out[(size_t)(bb * 64 + o) * HW_ + sp] = acc[jj][mtl][r] + bias;
            }
        }
    }
}

// ---------------------------------------------------------------------------
extern "C" void kernel_launch(void* const* d_in, const int* in_sizes, int n_in,
                              void* d_out, int out_size, void* d_ws, size_t ws_size,
                              hipStream_t stream) {
    const float* x     = (const float*)d_in[0];
    const float* offw  = (const float*)d_in[1];
    const float* offb  = (const float*)d_in[2];
    const float* mw    = (const float*)d_in[3];
    const float* mb    = (const float*)d_in[4];
    const float* convw = (const float*)d_in[5];
    const float* convb = (const float*)d_in[6];
    char* ws = (char*)d_ws;
    unsigned short* xt16 = (unsigned short*)(ws + XT_OFF);
    unsigned short* wfm  = (unsigned short*)(ws + WFM_OFF);
    unsigned short* wfo  = (unsigned short*)(ws + WFO_OFF);
    float* out = (float*)d_out;

    k_transpose<<<dim3(1152), dim3(256), 0, stream>>>(x, xt16);
    k_prepw    <<<dim3(27),   dim3(256), 0, stream>>>(offw, mw, convw, wfm, wfo);
    k_fused    <<<dim3(1152), dim3(256), 0, stream>>>(xt16, wfo, wfm, offb, mb, convb, out);
}

// Round 5
// 120.150 us; speedup vs baseline: 1.2591x; 1.0493x over previous
//
#include <hip/hip_runtime.h>
#include <hip/hip_fp16.h>
#include <cstddef>

#define B_   8
#define H_   96
#define W_   96
#define HW_  9216
#define PIX_ 73728

// LDS window geometry: rows hr-3..hr+5 (9), cols wc-4..wc+35 (40)
#define NWR    9
#define NWC    40
#define WINPX  360
#define NSLOTS 16

typedef __attribute__((ext_vector_type(8))) _Float16 halfx8;
typedef __attribute__((ext_vector_type(2))) __fp16 fp16x2_raw;
typedef __attribute__((ext_vector_type(4))) float floatx4;

// ws layout (byte offsets)
#define XT_OFF   0                          // fp16 NHWC x: PIX*64*2
#define WFM_OFF  (XT_OFF + PIX_*64*2)       // main W frags: 18*4*64*8 fp16
#define WFO_OFF  (WFM_OFF + 18*4*64*8*2)    // offs W frags: 18*2*64*8 fp16

__device__ __forceinline__ unsigned pk2h(float a, float b) {
    fp16x2_raw h = __builtin_amdgcn_cvt_pkrtz(a, b);
    union { fp16x2_raw h2; unsigned u; } t; t.h2 = h; return t.u;
}
__device__ __forceinline__ halfx8 uph8(uint4 u) {
    union { uint4 u4; halfx8 h; } t; t.u4 = u; return t.h;
}
__device__ __forceinline__ halfx8 splat8(unsigned d) {
    union { unsigned u[4]; halfx8 h; } t;
    t.u[0] = d; t.u[1] = d; t.u[2] = d; t.u[3] = d; return t.h;
}
__device__ __forceinline__ void async_ld16(const void* g, void* l) {
    __builtin_amdgcn_global_load_lds((const __attribute__((address_space(1))) void*)g,
                                     (__attribute__((address_space(3))) void*)l,
                                     16, 0, 0);
}

// ---------------------------------------------------------------------------
// NCHW f32 -> NHWC fp16 transpose via LDS tile; tail blocks pack weights.
__global__ __launch_bounds__(256) void k_transpose(const float* __restrict__ x,
                                                   unsigned short* __restrict__ xt,
                                                   const float* __restrict__ offw,
                                                   const float* __restrict__ mw,
                                                   const float* __restrict__ convw,
                                                   unsigned short* __restrict__ wfm,
                                                   unsigned short* __restrict__ wfo) {
    if (blockIdx.x >= 1152) {
        // ---- weight-prep branch (27 blocks) ----
        int g = (blockIdx.x - 1152) * 256 + threadIdx.x;
        if (g < 4608) {
            int lane = g & 63, mtks = g >> 6;
            int mt = mtks & 3, ks = mtks >> 2;
            int o = mt * 16 + (lane & 15), quad = lane >> 4;
            float v[8];
            #pragma unroll
            for (int j = 0; j < 8; ++j) {
                int k = ks * 32 + quad * 8 + j;
                int t = k / 64, c = k % 64;
                v[j] = convw[(size_t)(o * 64 + c) * 9 + t];
            }
            uint4 pk;
            pk.x = pk2h(v[0], v[1]); pk.y = pk2h(v[2], v[3]);
            pk.z = pk2h(v[4], v[5]); pk.w = pk2h(v[6], v[7]);
            *(uint4*)(wfm + (size_t)g * 8) = pk;
        } else if (g < 4608 + 2304) {
            int g2 = g - 4608;
            int lane = g2 & 63, mtks = g2 >> 6;
            int mt = mtks & 1, ks = mtks >> 1;
            int m = mt * 16 + (lane & 15), quad = lane >> 4;
            float v[8];
            #pragma unroll
            for (int j = 0; j < 8; ++j) {
                int k = ks * 32 + quad * 8 + j;
                int t = k / 64, c = k % 64;
                float f = 0.f;
                if (m < 18)      f = offw[(size_t)(m * 64 + c) * 9 + t];
                else if (m < 27) f = mw[(size_t)((m - 18) * 64 + c) * 9 + t];
                v[j] = f;
            }
            uint4 pk;
            pk.x = pk2h(v[0], v[1]); pk.y = pk2h(v[2], v[3]);
            pk.z = pk2h(v[4], v[5]); pk.w = pk2h(v[6], v[7]);
            *(uint4*)(wfo + (size_t)g2 * 8) = pk;
        }
        return;
    }

    __shared__ float tile[64 * 65];
    int bb  = blockIdx.x / 144;
    int sp0 = (blockIdx.x % 144) * 64;
    int t = threadIdx.x;
    int s4 = (t & 15) * 4, cq = t >> 4;
    #pragma unroll
    for (int i = 0; i < 4; ++i) {
        int c = cq + 16 * i;
        float4 v = *(const float4*)&x[(size_t)(bb * 64 + c) * HW_ + sp0 + s4];
        tile[c * 65 + s4 + 0] = v.x;
        tile[c * 65 + s4 + 1] = v.y;
        tile[c * 65 + s4 + 2] = v.z;
        tile[c * 65 + s4 + 3] = v.w;
    }
    __syncthreads();
    // each lane packs 8 channels of one pixel -> 1KB contiguous per wave-store
    int c8 = t & 7, sgrp = t >> 3;      // sgrp 0..31
    #pragma unroll
    for (int i = 0; i < 2; ++i) {
        int s2 = i * 32 + sgrp;
        uint4 pk;
        pk.x = pk2h(tile[(c8 * 8 + 0) * 65 + s2], tile[(c8 * 8 + 1) * 65 + s2]);
        pk.y = pk2h(tile[(c8 * 8 + 2) * 65 + s2], tile[(c8 * 8 + 3) * 65 + s2]);
        pk.z = pk2h(tile[(c8 * 8 + 4) * 65 + s2], tile[(c8 * 8 + 5) * 65 + s2]);
        pk.w = pk2h(tile[(c8 * 8 + 6) * 65 + s2], tile[(c8 * 8 + 7) * 65 + s2]);
        *(uint4*)(xt + (size_t)(bb * HW_ + sp0 + s2) * 64 + c8 * 8) = pk;
    }
}

// ---------------------------------------------------------------------------
// Fused kernel. Block = 256 thr = 4 waves, owns 64 px (2 rows x 32 cols).
// x window DMA'd into LDS via global_load_lds (swizzle folded into source);
// phase-3 combine in packed fp16.
__global__ __launch_bounds__(256, 2) void k_fused(const unsigned short* __restrict__ xt,
                                                  const unsigned short* __restrict__ wfo,
                                                  const unsigned short* __restrict__ wfm,
                                                  const float* __restrict__ offb,
                                                  const float* __restrict__ mb,
                                                  const float* __restrict__ convb,
                                                  float* __restrict__ out) {
    __shared__ __align__(16) unsigned char s_win[(WINPX + NSLOTS) * 128];  // 48128 B
    __shared__ float s_off[27 * 66];                                       // 7128 B
    __shared__ __align__(16) unsigned char s_meta[64 * 9 * 16];            // 9216 B
    __shared__ int s_cnt;

    int tid = threadIdx.x;
    int w = tid >> 6, lane = tid & 63, col = lane & 15, quad = lane >> 4;
    int blk = blockIdx.x;
    int bb  = blk / 144;
    int rem = blk % 144;
    int hr  = (rem / 3) * 2;            // top row of the 2-row tile
    int wc  = (rem % 3) * 32;           // left col of the 32-col segment
    const unsigned short* xtb = xt + (size_t)bb * HW_ * 64;

    // ---- stage window: direct-to-LDS DMA, source pre-swizzled ----
    if (tid == 0) s_cnt = 0;
    {
        int p0  = lane >> 3;                    // pixel-within-group
        int cgx = (lane & 7) ^ p0;              // swizzled source ch-group
        for (int i = w; i < 45; i += 4) {       // 45 groups of 8 px, split by wave
            int p = i * 8 + p0;
            int wr = p / NWC, wcl = p - wr * NWC;
            int gr = hr - 3 + wr, gc = wc - 4 + wcl;
            int grc = min(max(gr, 0), 95), gcc = min(max(gc, 0), 95);
            const unsigned short* src = xtb + ((size_t)(grc * 96 + gcc) * 64 + cgx * 8);
            async_ld16(src, s_win + i * 1024);
        }
    }
    __syncthreads();
    // zero OOB pixels (provides the conv zero-padding; cheap, edge blocks only)
    for (int p = tid; p < WINPX; p += 256) {
        int wr = p / NWC, wcl = p - wr * NWC;
        int gr = hr - 3 + wr, gc = wc - 4 + wcl;
        if ((unsigned)gr >= 96u || (unsigned)gc >= 96u) {
            uint4 z = make_uint4(0, 0, 0, 0);
            #pragma unroll
            for (int cg = 0; cg < 8; ++cg)
                *(uint4*)(s_win + p * 128 + cg * 16) = z;
        }
    }
    __syncthreads();

    // ---- phase 1: offset/mod conv GEMM (B from LDS window) ----
    floatx4 aoff0 = (floatx4){0.f, 0.f, 0.f, 0.f};
    floatx4 aoff1 = (floatx4){0.f, 0.f, 0.f, 0.f};
    {
        int wr_base = 3 + (w >> 1);
        int wc_base = 4 + (w & 1) * 16 + col;
        #pragma unroll
        for (int t = 0; t < 9; ++t) {
            int dh = t / 3 - 1, dw = t % 3 - 1;
            int p = (wr_base + dh) * NWC + (wc_base + dw);
            int pb = p << 7, psw = (p & 7) << 4;
            #pragma unroll
            for (int ksl = 0; ksl < 2; ++ksl) {
                int ks = t * 2 + ksl;
                halfx8 a0 = *(const halfx8*)(wfo + ((size_t)(ks * 2 + 0) * 64 + lane) * 8);
                halfx8 a1 = *(const halfx8*)(wfo + ((size_t)(ks * 2 + 1) * 64 + lane) * 8);
                uint4 bvu = *(const uint4*)(s_win + pb + ((quad * 16 + ksl * 64) ^ psw));
                halfx8 bv = uph8(bvu);
                aoff0 = __builtin_amdgcn_mfma_f32_16x16x32_f16(a0, bv, aoff0, 0, 0, 0);
                aoff1 = __builtin_amdgcn_mfma_f32_16x16x32_f16(a1, bv, aoff1, 0, 0, 0);
            }
        }
    }
    #pragma unroll
    for (int r = 0; r < 4; ++r) {
        s_off[(quad * 4 + r) * 66 + (w * 16 + col)] = aoff0[r];
        int m = 16 + quad * 4 + r;
        if (m < 27) s_off[m * 66 + (w * 16 + col)] = aoff1[r];
    }
    __syncthreads();

    // ---- phase 2: bilinear metadata for 64 px x 9 n; LDS-window indices ----
    for (int id = tid; id < 576; id += 256) {
        int px = id & 63, n = id >> 6;
        float ox = s_off[n * 66 + px]        + offb[n];
        float oy = s_off[(9 + n) * 66 + px]  + offb[9 + n];
        float mv = s_off[(18 + n) * 66 + px] + mb[n];
        float modv = 1.f / (1.f + __expf(-mv));
        int prow = hr + (px >> 5), pcol = wc + (px & 31);
        float pxx = ox + (float)(prow + 1) + (float)(n / 3 - 1);
        float pyy = oy + (float)(pcol + 1) + (float)(n % 3 - 1);
        float flx = floorf(pxx), fly = floorf(pyy);
        float tlxf = fminf(fmaxf(flx,       0.f), 97.f);
        float tlyf = fminf(fmaxf(fly,       0.f), 97.f);
        float brxf = fminf(fmaxf(flx + 1.f, 0.f), 97.f);
        float bryf = fminf(fmaxf(fly + 1.f, 0.f), 97.f);
        float pcx  = fminf(fmaxf(pxx, 0.f), 97.f);
        float pcy  = fminf(fmaxf(pyy, 0.f), 97.f);
        float gx0 = 1.f + tlxf - pcx;
        float gx1 = 1.f - (brxf - pcx);
        float gy0 = 1.f + tlyf - pcy;
        float gy1 = 1.f - (bryf - pcy);
        int tlx = (int)tlxf, tly = (int)tlyf, brx = (int)brxf, bry = (int)bryf;
        int   qxs[4] = {tlx, tlx, brx, brx};
        int   qys[4] = {tly, bry, tly, bry};
        float gs4[4] = {gx0 * gy0, gx0 * gy1, gx1 * gy0, gx1 * gy1};
        unsigned short si[4]; unsigned short hg[4];
        #pragma unroll
        for (int c4 = 0; c4 < 4; ++c4) {
            int qx = qxs[c4], qy = qys[c4];
            bool valid = (qx >= 1) && (qx <= 96) && (qy >= 1) && (qy <= 96);
            int gr = qx - 1, gc = qy - 1;
            int wr = gr - (hr - 3), wcl = gc - (wc - 4);
            bool inwin = ((unsigned)wr < (unsigned)NWR) && ((unsigned)wcl < (unsigned)NWC);
            unsigned short idxv; float gvf;
            if (inwin) {
                idxv = (unsigned short)(wr * NWC + wcl);   // zeros staged for out-of-image
                gvf = gs4[c4] * modv;
            } else if (!valid) {
                idxv = 0; gvf = 0.f;
            } else {
                // rare: valid corner outside window -> copy into LDS overflow slot
                int s = atomicAdd(&s_cnt, 1);
                int gidx = gr * 96 + gc;
                if (s < NSLOTS) {
                    int ps = WINPX + s;
                    #pragma unroll
                    for (int ch = 0; ch < 8; ++ch) {
                        uint4 v = *(const uint4*)(xtb + (size_t)gidx * 64 + ch * 8);
                        *(uint4*)(s_win + (size_t)ps * 128 + ((ch ^ (ps & 7)) * 16)) = v;
                    }
                    idxv = (unsigned short)ps;
                } else {
                    idxv = (unsigned short)(0x8000u | (unsigned)gidx);  // global fallback tag
                }
                gvf = gs4[c4] * modv;
            }
            si[c4] = idxv;
            hg[c4] = __half_as_ushort(__float2half_rn(gvf));
        }
        uint4 mw4;
        mw4.x = si[0] | ((unsigned)si[1] << 16);
        mw4.y = si[2] | ((unsigned)si[3] << 16);
        mw4.z = hg[0] | ((unsigned)hg[1] << 16);
        mw4.w = hg[2] | ((unsigned)hg[3] << 16);
        *(uint4*)(s_meta + ((size_t)px * 9 + n) * 16) = mw4;
    }
    __syncthreads();

    // ---- phase 3: main contraction; packed-fp16 combine ----
    int mth = w & 1, pg = w >> 1;      // wave: o-half mth, px-half pg
    floatx4 acc[2][2];
    #pragma unroll
    for (int jj = 0; jj < 2; ++jj)
        #pragma unroll
        for (int mtl = 0; mtl < 2; ++mtl) acc[jj][mtl] = (floatx4){0.f, 0.f, 0.f, 0.f};

    int qk0 = quad * 16, qk1 = quad * 16 + 64;

    #pragma unroll
    for (int n = 0; n < 9; ++n) {
        halfx8 af00 = *(const halfx8*)(wfm + ((size_t)((n * 2 + 0) * 4 + mth * 2 + 0) * 64 + lane) * 8);
        halfx8 af01 = *(const halfx8*)(wfm + ((size_t)((n * 2 + 0) * 4 + mth * 2 + 1) * 64 + lane) * 8);
        halfx8 af10 = *(const halfx8*)(wfm + ((size_t)((n * 2 + 1) * 4 + mth * 2 + 0) * 64 + lane) * 8);
        halfx8 af11 = *(const halfx8*)(wfm + ((size_t)((n * 2 + 1) * 4 + mth * 2 + 1) * 64 + lane) * 8);
        #pragma unroll
        for (int jj = 0; jj < 2; ++jj) {
            int px = pg * 32 + jj * 16 + col;
            uint4 mu = *(const uint4*)(s_meta + ((size_t)px * 9 + n) * 16);
            unsigned i0 = mu.x & 0xFFFFu, i1 = mu.x >> 16;
            unsigned i2 = mu.y & 0xFFFFu, i3 = mu.y >> 16;
            int pm0 = (i0 & 0x8000u) ? 0 : (int)i0;
            int pm1 = (i1 & 0x8000u) ? 0 : (int)i1;
            int pm2 = (i2 & 0x8000u) ? 0 : (int)i2;
            int pm3 = (i3 & 0x8000u) ? 0 : (int)i3;
            int b0 = pm0 << 7, s0 = (pm0 & 7) << 4;
            int b1 = pm1 << 7, s1 = (pm1 & 7) << 4;
            int b2 = pm2 << 7, s2 = (pm2 & 7) << 4;
            int b3 = pm3 << 7, s3 = (pm3 & 7) << 4;
            uint4 cA0 = *(const uint4*)(s_win + b0 + (qk0 ^ s0));
            uint4 cA1 = *(const uint4*)(s_win + b1 + (qk0 ^ s1));
            uint4 cA2 = *(const uint4*)(s_win + b2 + (qk0 ^ s2));
            uint4 cA3 = *(const uint4*)(s_win + b3 + (qk0 ^ s3));
            uint4 cB0 = *(const uint4*)(s_win + b0 + (qk1 ^ s0));
            uint4 cB1 = *(const uint4*)(s_win + b1 + (qk1 ^ s1));
            uint4 cB2 = *(const uint4*)(s_win + b2 + (qk1 ^ s2));
            uint4 cB3 = *(const uint4*)(s_win + b3 + (qk1 ^ s3));
            if (__any((int)((i0 | i1 | i2 | i3) & 0x8000u))) {
                // ultra-rare global fallback (slot overflow)
                if (i0 & 0x8000u) { size_t ga = (size_t)(i0 & 0x3FFFu) * 64 + quad * 8;
                    cA0 = *(const uint4*)(xtb + ga); cB0 = *(const uint4*)(xtb + ga + 32); }
                if (i1 & 0x8000u) { size_t ga = (size_t)(i1 & 0x3FFFu) * 64 + quad * 8;
                    cA1 = *(const uint4*)(xtb + ga); cB1 = *(const uint4*)(xtb + ga + 32); }
                if (i2 & 0x8000u) { size_t ga = (size_t)(i2 & 0x3FFFu) * 64 + quad * 8;
                    cA2 = *(const uint4*)(xtb + ga); cB2 = *(const uint4*)(xtb + ga + 32); }
                if (i3 & 0x8000u) { size_t ga = (size_t)(i3 & 0x3FFFu) * 64 + quad * 8;
                    cA3 = *(const uint4*)(xtb + ga); cB3 = *(const uint4*)(xtb + ga + 32); }
            }
            // splat each half g to a packed pair, then pure v_pk_mul/fma_f16
            unsigned gl0 = (mu.z & 0xFFFFu) | (mu.z << 16);
            unsigned gl1 = (mu.z >> 16) | (mu.z & 0xFFFF0000u);
            unsigned gl2 = (mu.w & 0xFFFFu) | (mu.w << 16);
            unsigned gl3 = (mu.w >> 16) | (mu.w & 0xFFFF0000u);
            halfx8 g0 = splat8(gl0), g1 = splat8(gl1), g2 = splat8(gl2), g3 = splat8(gl3);
            halfx8 vA = uph8(cA0) * g0;
            vA += uph8(cA1) * g1; vA += uph8(cA2) * g2; vA += uph8(cA3) * g3;
            halfx8 vB = uph8(cB0) * g0;
            vB += uph8(cB1) * g1; vB += uph8(cB2) * g2; vB += uph8(cB3) * g3;
            acc[jj][0] = __builtin_amdgcn_mfma_f32_16x16x32_f16(af00, vA, acc[jj][0], 0, 0, 0);
            acc[jj][1] = __builtin_amdgcn_mfma_f32_16x16x32_f16(af01, vA, acc[jj][1], 0, 0, 0);
            acc[jj][0] = __builtin_amdgcn_mfma_f32_16x16x32_f16(af10, vB, acc[jj][0], 0, 0, 0);
            acc[jj][1] = __builtin_amdgcn_mfma_f32_16x16x32_f16(af11, vB, acc[jj][1], 0, 0, 0);
        }
    }

    // ---- epilogue ----
    int prow = hr + pg;
    #pragma unroll
    for (int mtl = 0; mtl < 2; ++mtl) {
        float4 cb4 = *(const float4*)&convb[mth * 32 + mtl * 16 + quad * 4];
        #pragma unroll
        for (int jj = 0; jj < 2; ++jj) {
            int sp = prow * 96 + wc + jj * 16 + col;
            #pragma unroll
            for (int r = 0; r < 4; ++r) {
                int o = mth * 32 + mtl * 16 + quad * 4 + r;
                float bias = (r == 0) ? cb4.x : (r == 1) ? cb4.y : (r == 2) ? cb4.z : cb4.w;
                out[(size_t)(bb * 64 + o) * HW_ + sp] = acc[jj][mtl][r] + bias;
            }
        }
    }
}

// ---------------------------------------------------------------------------
extern "C" void kernel_launch(void* const* d_in, const int* in_sizes, int n_in,
                              void* d_out, int out_size, void* d_ws, size_t ws_size,
                              hipStream_t stream) {
    const float* x     = (const float*)d_in[0];
    const float* offw  = (const float*)d_in[1];
    const float* offb  = (const float*)d_in[2];
    const float* mw    = (const float*)d_in[3];
    const float* mb    = (const float*)d_in[4];
    const float* convw = (const float*)d_in[5];
    const float* convb = (const float*)d_in[6];
    char* ws = (char*)d_ws;
    unsigned short* xt16 = (unsigned short*)(ws + XT_OFF);
    unsigned short* wfm  = (unsigned short*)(ws + WFM_OFF);
    unsigned short* wfo  = (unsigned short*)(ws + WFO_OFF);
    float* out = (float*)d_out;

    k_transpose<<<dim3(1152 + 27), dim3(256), 0, stream>>>(x, xt16, offw, mw, convw, wfm, wfo);
    k_fused    <<<dim3(1152),      dim3(256), 0, stream>>>(xt16, wfo, wfm, offb, mb, convb, out);
}

// Round 6
// 115.718 us; speedup vs baseline: 1.3073x; 1.0383x over previous
//
#include <hip/hip_runtime.h>
#include <hip/hip_fp16.h>
#include <cstddef>

#define B_   8
#define H_   96
#define W_   96
#define HW_  9216
#define PIX_ 73728

// LDS window geometry: rows hr-2..hr+4 (7), cols wc-3..wc+34 (38)
#define NWR    7
#define NWC    38
#define WINPX  266
#define NSLOTS 22

typedef __attribute__((ext_vector_type(8))) _Float16 halfx8;
typedef __attribute__((ext_vector_type(2))) __fp16 fp16x2_raw;
typedef __attribute__((ext_vector_type(4))) float floatx4;

// ws layout (byte offsets)
#define XT_OFF   0                          // fp16 NHWC x: PIX*64*2
#define WFM_OFF  (XT_OFF + PIX_*64*2)       // main W frags: 18*4*64*8 fp16
#define WFO_OFF  (WFM_OFF + 18*4*64*8*2)    // offs W frags: 18*2*64*8 fp16
#define WZ_OFF   (WFO_OFF + 18*2*64*8*2)    // 128B zero page

__device__ __forceinline__ unsigned pk2h(float a, float b) {
    fp16x2_raw h = __builtin_amdgcn_cvt_pkrtz(a, b);
    union { fp16x2_raw h2; unsigned u; } t; t.h2 = h; return t.u;
}
__device__ __forceinline__ halfx8 uph8(uint4 u) {
    union { uint4 u4; halfx8 h; } t; t.u4 = u; return t.h;
}
__device__ __forceinline__ halfx8 splat8(unsigned d) {
    union { unsigned u[4]; halfx8 h; } t;
    t.u[0] = d; t.u[1] = d; t.u[2] = d; t.u[3] = d; return t.h;
}
__device__ __forceinline__ void async_ld16(const void* g, void* l) {
    __builtin_amdgcn_global_load_lds((const __attribute__((address_space(1))) void*)g,
                                     (__attribute__((address_space(3))) void*)l,
                                     16, 0, 0);
}

// ---------------------------------------------------------------------------
// NCHW f32 -> NHWC fp16 transpose via LDS tile; tail blocks pack weights.
__global__ __launch_bounds__(256) void k_transpose(const float* __restrict__ x,
                                                   unsigned short* __restrict__ xt,
                                                   const float* __restrict__ offw,
                                                   const float* __restrict__ mw,
                                                   const float* __restrict__ convw,
                                                   unsigned short* __restrict__ wfm,
                                                   unsigned short* __restrict__ wfo,
                                                   unsigned short* __restrict__ wz) {
    if (blockIdx.x >= 1152) {
        // ---- weight-prep branch (28 blocks) ----
        int g = (blockIdx.x - 1152) * 256 + threadIdx.x;
        if (g < 4608) {
            int lane = g & 63, mtks = g >> 6;
            int mt = mtks & 3, ks = mtks >> 2;
            int o = mt * 16 + (lane & 15), quad = lane >> 4;
            float v[8];
            #pragma unroll
            for (int j = 0; j < 8; ++j) {
                int k = ks * 32 + quad * 8 + j;
                int t = k / 64, c = k % 64;
                v[j] = convw[(size_t)(o * 64 + c) * 9 + t];
            }
            uint4 pk;
            pk.x = pk2h(v[0], v[1]); pk.y = pk2h(v[2], v[3]);
            pk.z = pk2h(v[4], v[5]); pk.w = pk2h(v[6], v[7]);
            *(uint4*)(wfm + (size_t)g * 8) = pk;
        } else if (g < 4608 + 2304) {
            int g2 = g - 4608;
            int lane = g2 & 63, mtks = g2 >> 6;
            int mt = mtks & 1, ks = mtks >> 1;
            int m = mt * 16 + (lane & 15), quad = lane >> 4;
            float v[8];
            #pragma unroll
            for (int j = 0; j < 8; ++j) {
                int k = ks * 32 + quad * 8 + j;
                int t = k / 64, c = k % 64;
                float f = 0.f;
                if (m < 18)      f = offw[(size_t)(m * 64 + c) * 9 + t];
                else if (m < 27) f = mw[(size_t)((m - 18) * 64 + c) * 9 + t];
                v[j] = f;
            }
            uint4 pk;
            pk.x = pk2h(v[0], v[1]); pk.y = pk2h(v[2], v[3]);
            pk.z = pk2h(v[4], v[5]); pk.w = pk2h(v[6], v[7]);
            *(uint4*)(wfo + (size_t)g2 * 8) = pk;
        } else if (g < 4608 + 2304 + 8) {
            // zero page (128 B)
            uint4 z = make_uint4(0, 0, 0, 0);
            *(uint4*)(wz + (size_t)(g - 6912) * 8) = z;
        }
        return;
    }

    __shared__ float tile[64 * 65];
    int bb  = blockIdx.x / 144;
    int sp0 = (blockIdx.x % 144) * 64;
    int t = threadIdx.x;
    int s4 = (t & 15) * 4, cq = t >> 4;
    #pragma unroll
    for (int i = 0; i < 4; ++i) {
        int c = cq + 16 * i;
        float4 v = *(const float4*)&x[(size_t)(bb * 64 + c) * HW_ + sp0 + s4];
        tile[c * 65 + s4 + 0] = v.x;
        tile[c * 65 + s4 + 1] = v.y;
        tile[c * 65 + s4 + 2] = v.z;
        tile[c * 65 + s4 + 3] = v.w;
    }
    __syncthreads();
    // each lane packs 8 channels of one pixel -> 1KB contiguous per wave-store
    int c8 = t & 7, sgrp = t >> 3;      // sgrp 0..31
    #pragma unroll
    for (int i = 0; i < 2; ++i) {
        int s2 = i * 32 + sgrp;
        uint4 pk;
        pk.x = pk2h(tile[(c8 * 8 + 0) * 65 + s2], tile[(c8 * 8 + 1) * 65 + s2]);
        pk.y = pk2h(tile[(c8 * 8 + 2) * 65 + s2], tile[(c8 * 8 + 3) * 65 + s2]);
        pk.z = pk2h(tile[(c8 * 8 + 4) * 65 + s2], tile[(c8 * 8 + 5) * 65 + s2]);
        pk.w = pk2h(tile[(c8 * 8 + 6) * 65 + s2], tile[(c8 * 8 + 7) * 65 + s2]);
        *(uint4*)(xt + (size_t)(bb * HW_ + sp0 + s2) * 64 + c8 * 8) = pk;
    }
}

// ---------------------------------------------------------------------------
// Fused kernel. Block = 256 thr = 4 waves, owns 64 px (2 rows x 32 cols).
// 7x38 window DMA'd into LDS (swizzle folded into source; OOB -> zero page).
// LDS 53.2 KB -> 3 blocks/CU.
__global__ __launch_bounds__(256, 3) void k_fused(const unsigned short* __restrict__ xt,
                                                  const unsigned short* __restrict__ wfo,
                                                  const unsigned short* __restrict__ wfm,
                                                  const float* __restrict__ offb,
                                                  const float* __restrict__ mb,
                                                  const float* __restrict__ convb,
                                                  const unsigned short* __restrict__ wz,
                                                  float* __restrict__ out) {
    __shared__ __align__(16) unsigned char s_win[(WINPX + NSLOTS) * 128];  // 36864 B
    __shared__ float s_off[27 * 66];                                       // 7128 B
    __shared__ __align__(16) unsigned char s_meta[64 * 9 * 16];            // 9216 B
    __shared__ int s_cnt;

    int tid = threadIdx.x;
    int w = tid >> 6, lane = tid & 63, col = lane & 15, quad = lane >> 4;
    int blk = blockIdx.x;
    int bb  = blk / 144;
    int rem = blk % 144;
    int hr  = (rem / 3) * 2;            // top row of the 2-row tile
    int wc  = (rem % 3) * 32;           // left col of the 32-col segment
    const unsigned short* xtb = xt + (size_t)bb * HW_ * 64;

    // ---- stage window: direct-to-LDS DMA, source pre-swizzled; OOB -> zeros ----
    if (tid == 0) s_cnt = 0;
    {
        int p0  = lane >> 3;                    // pixel-within-group
        int cgx = (lane & 7) ^ p0;              // swizzled source ch-group
        const unsigned short* wzp = wz + cgx * 8;
        for (int i = w; i < 34; i += 4) {       // 34 groups of 8 px, split by wave
            int p = i * 8 + p0;
            int wr = p / NWC, wcl = p - wr * NWC;
            int gr = hr - 2 + wr, gc = wc - 3 + wcl;
            bool ok = (p < WINPX) && ((unsigned)gr < 96u) && ((unsigned)gc < 96u);
            const unsigned short* src = ok ? (xtb + ((size_t)(gr * 96 + gc) * 64 + cgx * 8)) : wzp;
            async_ld16(src, s_win + i * 1024);
        }
    }
    __syncthreads();

    // ---- phase 1: offset/mod conv GEMM (B from LDS window) ----
    floatx4 aoff0 = (floatx4){0.f, 0.f, 0.f, 0.f};
    floatx4 aoff1 = (floatx4){0.f, 0.f, 0.f, 0.f};
    {
        int wr_base = 2 + (w >> 1);
        int wc_base = 3 + (w & 1) * 16 + col;
        #pragma unroll
        for (int t = 0; t < 9; ++t) {
            int dh = t / 3 - 1, dw = t % 3 - 1;
            int p = (wr_base + dh) * NWC + (wc_base + dw);
            int pb = p << 7, psw = (p & 7) << 4;
            #pragma unroll
            for (int ksl = 0; ksl < 2; ++ksl) {
                int ks = t * 2 + ksl;
                halfx8 a0 = *(const halfx8*)(wfo + ((size_t)(ks * 2 + 0) * 64 + lane) * 8);
                halfx8 a1 = *(const halfx8*)(wfo + ((size_t)(ks * 2 + 1) * 64 + lane) * 8);
                uint4 bvu = *(const uint4*)(s_win + pb + ((quad * 16 + ksl * 64) ^ psw));
                halfx8 bv = uph8(bvu);
                aoff0 = __builtin_amdgcn_mfma_f32_16x16x32_f16(a0, bv, aoff0, 0, 0, 0);
                aoff1 = __builtin_amdgcn_mfma_f32_16x16x32_f16(a1, bv, aoff1, 0, 0, 0);
            }
        }
    }
    #pragma unroll
    for (int r = 0; r < 4; ++r) {
        s_off[(quad * 4 + r) * 66 + (w * 16 + col)] = aoff0[r];
        int m = 16 + quad * 4 + r;
        if (m < 27) s_off[m * 66 + (w * 16 + col)] = aoff1[r];
    }
    __syncthreads();

    // ---- phase 2: bilinear metadata for 64 px x 9 n; LDS-window indices ----
    for (int id = tid; id < 576; id += 256) {
        int px = id & 63, n = id >> 6;
        float ox = s_off[n * 66 + px]        + offb[n];
        float oy = s_off[(9 + n) * 66 + px]  + offb[9 + n];
        float mv = s_off[(18 + n) * 66 + px] + mb[n];
        float modv = 1.f / (1.f + __expf(-mv));
        int prow = hr + (px >> 5), pcol = wc + (px & 31);
        float pxx = ox + (float)(prow + 1) + (float)(n / 3 - 1);
        float pyy = oy + (float)(pcol + 1) + (float)(n % 3 - 1);
        float flx = floorf(pxx), fly = floorf(pyy);
        float tlxf = fminf(fmaxf(flx,       0.f), 97.f);
        float tlyf = fminf(fmaxf(fly,       0.f), 97.f);
        float brxf = fminf(fmaxf(flx + 1.f, 0.f), 97.f);
        float bryf = fminf(fmaxf(fly + 1.f, 0.f), 97.f);
        float pcx  = fminf(fmaxf(pxx, 0.f), 97.f);
        float pcy  = fminf(fmaxf(pyy, 0.f), 97.f);
        float gx0 = 1.f + tlxf - pcx;
        float gx1 = 1.f - (brxf - pcx);
        float gy0 = 1.f + tlyf - pcy;
        float gy1 = 1.f - (bryf - pcy);
        int tlx = (int)tlxf, tly = (int)tlyf, brx = (int)brxf, bry = (int)bryf;
        int   qxs[4] = {tlx, tlx, brx, brx};
        int   qys[4] = {tly, bry, tly, bry};
        float gs4[4] = {gx0 * gy0, gx0 * gy1, gx1 * gy0, gx1 * gy1};
        unsigned short si[4]; unsigned short hg[4];
        #pragma unroll
        for (int c4 = 0; c4 < 4; ++c4) {
            int qx = qxs[c4], qy = qys[c4];
            bool valid = (qx >= 1) && (qx <= 96) && (qy >= 1) && (qy <= 96);
            int gr = qx - 1, gc = qy - 1;
            int wr = gr - (hr - 2), wcl = gc - (wc - 3);
            bool inwin = ((unsigned)wr < (unsigned)NWR) && ((unsigned)wcl < (unsigned)NWC);
            unsigned short idxv; float gvf;
            if (inwin) {
                idxv = (unsigned short)(wr * NWC + wcl);   // zeros staged for out-of-image
                gvf = gs4[c4] * modv;
            } else if (!valid) {
                idxv = 0; gvf = 0.f;
            } else {
                // rare: valid corner outside window -> copy into LDS overflow slot
                int s = atomicAdd(&s_cnt, 1);
                int gidx = gr * 96 + gc;
                if (s < NSLOTS) {
                    int ps = WINPX + s;
                    #pragma unroll
                    for (int ch = 0; ch < 8; ++ch) {
                        uint4 v = *(const uint4*)(xtb + (size_t)gidx * 64 + ch * 8);
                        *(uint4*)(s_win + (size_t)ps * 128 + ((ch ^ (ps & 7)) * 16)) = v;
                    }
                    idxv = (unsigned short)ps;
                } else {
                    idxv = (unsigned short)(0x8000u | (unsigned)gidx);  // global fallback tag
                }
                gvf = gs4[c4] * modv;
            }
            si[c4] = idxv;
            hg[c4] = __half_as_ushort(__float2half_rn(gvf));
        }
        uint4 mw4;
        mw4.x = si[0] | ((unsigned)si[1] << 16);
        mw4.y = si[2] | ((unsigned)si[3] << 16);
        mw4.z = hg[0] | ((unsigned)hg[1] << 16);
        mw4.w = hg[2] | ((unsigned)hg[3] << 16);
        *(uint4*)(s_meta + ((size_t)px * 9 + n) * 16) = mw4;
    }
    __syncthreads();

    // ---- phase 3: main contraction; packed-fp16 combine ----
    int mth = w & 1, pg = w >> 1;      // wave: o-half mth, px-half pg
    floatx4 acc[2][2];
    #pragma unroll
    for (int jj = 0; jj < 2; ++jj)
        #pragma unroll
        for (int mtl = 0; mtl < 2; ++mtl) acc[jj][mtl] = (floatx4){0.f, 0.f, 0.f, 0.f};

    int qk0 = quad * 16, qk1 = quad * 16 + 64;

    #pragma unroll
    for (int n = 0; n < 9; ++n) {
        halfx8 af00 = *(const halfx8*)(wfm + ((size_t)((n * 2 + 0) * 4 + mth * 2 + 0) * 64 + lane) * 8);
        halfx8 af01 = *(const halfx8*)(wfm + ((size_t)((n * 2 + 0) * 4 + mth * 2 + 1) * 64 + lane) * 8);
        halfx8 af10 = *(const halfx8*)(wfm + ((size_t)((n * 2 + 1) * 4 + mth * 2 + 0) * 64 + lane) * 8);
        halfx8 af11 = *(const halfx8*)(wfm + ((size_t)((n * 2 + 1) * 4 + mth * 2 + 1) * 64 + lane) * 8);
        #pragma unroll
        for (int jj = 0; jj < 2; ++jj) {
            int px = pg * 32 + jj * 16 + col;
            uint4 mu = *(const uint4*)(s_meta + ((size_t)px * 9 + n) * 16);
            unsigned i0 = mu.x & 0xFFFFu, i1 = mu.x >> 16;
            unsigned i2 = mu.y & 0xFFFFu, i3 = mu.y >> 16;
            int pm0 = (i0 & 0x8000u) ? 0 : (int)i0;
            int pm1 = (i1 & 0x8000u) ? 0 : (int)i1;
            int pm2 = (i2 & 0x8000u) ? 0 : (int)i2;
            int pm3 = (i3 & 0x8000u) ? 0 : (int)i3;
            int b0 = pm0 << 7, s0 = (pm0 & 7) << 4;
            int b1 = pm1 << 7, s1 = (pm1 & 7) << 4;
            int b2 = pm2 << 7, s2 = (pm2 & 7) << 4;
            int b3 = pm3 << 7, s3 = (pm3 & 7) << 4;
            uint4 cA0 = *(const uint4*)(s_win + b0 + (qk0 ^ s0));
            uint4 cA1 = *(const uint4*)(s_win + b1 + (qk0 ^ s1));
            uint4 cA2 = *(const uint4*)(s_win + b2 + (qk0 ^ s2));
            uint4 cA3 = *(const uint4*)(s_win + b3 + (qk0 ^ s3));
            uint4 cB0 = *(const uint4*)(s_win + b0 + (qk1 ^ s0));
            uint4 cB1 = *(const uint4*)(s_win + b1 + (qk1 ^ s1));
            uint4 cB2 = *(const uint4*)(s_win + b2 + (qk1 ^ s2));
            uint4 cB3 = *(const uint4*)(s_win + b3 + (qk1 ^ s3));
            if (__any((int)((i0 | i1 | i2 | i3) & 0x8000u))) {
                // ultra-rare global fallback (slot overflow)
                if (i0 & 0x8000u) { size_t ga = (size_t)(i0 & 0x3FFFu) * 64 + quad * 8;
                    cA0 = *(const uint4*)(xtb + ga); cB0 = *(const uint4*)(xtb + ga + 32); }
                if (i1 & 0x8000u) { size_t ga = (size_t)(i1 & 0x3FFFu) * 64 + quad * 8;
                    cA1 = *(const uint4*)(xtb + ga); cB1 = *(const uint4*)(xtb + ga + 32); }
                if (i2 & 0x8000u) { size_t ga = (size_t)(i2 & 0x3FFFu) * 64 + quad * 8;
                    cA2 = *(const uint4*)(xtb + ga); cB2 = *(const uint4*)(xtb + ga + 32); }
                if (i3 & 0x8000u) { size_t ga = (size_t)(i3 & 0x3FFFu) * 64 + quad * 8;
                    cA3 = *(const uint4*)(xtb + ga); cB3 = *(const uint4*)(xtb + ga + 32); }
            }
            // splat each half g to a packed pair, then pure v_pk_mul/fma_f16
            unsigned gl0 = (mu.z & 0xFFFFu) | (mu.z << 16);
            unsigned gl1 = (mu.z >> 16) | (mu.z & 0xFFFF0000u);
            unsigned gl2 = (mu.w & 0xFFFFu) | (mu.w << 16);
            unsigned gl3 = (mu.w >> 16) | (mu.w & 0xFFFF0000u);
            halfx8 g0 = splat8(gl0), g1 = splat8(gl1), g2 = splat8(gl2), g3 = splat8(gl3);
            halfx8 vA = uph8(cA0) * g0;
            vA += uph8(cA1) * g1; vA += uph8(cA2) * g2; vA += uph8(cA3) * g3;
            halfx8 vB = uph8(cB0) * g0;
            vB += uph8(cB1) * g1; vB += uph8(cB2) * g2; vB += uph8(cB3) * g3;
            acc[jj][0] = __builtin_amdgcn_mfma_f32_16x16x32_f16(af00, vA, acc[jj][0], 0, 0, 0);
            acc[jj][1] = __builtin_amdgcn_mfma_f32_16x16x32_f16(af01, vA, acc[jj][1], 0, 0, 0);
            acc[jj][0] = __builtin_amdgcn_mfma_f32_16x16x32_f16(af10, vB, acc[jj][0], 0, 0, 0);
            acc[jj][1] = __builtin_amdgcn_mfma_f32_16x16x32_f16(af11, vB, acc[jj][1], 0, 0, 0);
        }
    }

    // ---- epilogue ----
    int prow = hr + pg;
    #pragma unroll
    for (int mtl = 0; mtl < 2; ++mtl) {
        float4 cb4 = *(const float4*)&convb[mth * 32 + mtl * 16 + quad * 4];
        #pragma unroll
        for (int jj = 0; jj < 2; ++jj) {
            int sp = prow * 96 + wc + jj * 16 + col;
            #pragma unroll
            for (int r = 0; r < 4; ++r) {
                int o = mth * 32 + mtl * 16 + quad * 4 + r;
                float bias = (r == 0) ? cb4.x : (r == 1) ? cb4.y : (r == 2) ? cb4.z : cb4.w;
                out[(size_t)(bb * 64 + o) * HW_ + sp] = acc[jj][mtl][r] + bias;
            }
        }
    }
}

// ---------------------------------------------------------------------------
extern "C" void kernel_launch(void* const* d_in, const int* in_sizes, int n_in,
                              void* d_out, int out_size, void* d_ws, size_t ws_size,
                              hipStream_t stream) {
    const float* x     = (const float*)d_in[0];
    const float* offw  = (const float*)d_in[1];
    const float* offb  = (const float*)d_in[2];
    const float* mw    = (const float*)d_in[3];
    const float* mb    = (const float*)d_in[4];
    const float* convw = (const float*)d_in[5];
    const float* convb = (const float*)d_in[6];
    char* ws = (char*)d_ws;
    unsigned short* xt16 = (unsigned short*)(ws + XT_OFF);
    unsigned short* wfm  = (unsigned short*)(ws + WFM_OFF);
    unsigned short* wfo  = (unsigned short*)(ws + WFO_OFF);
    unsigned short* wz   = (unsigned short*)(ws + WZ_OFF);
    float* out = (float*)d_out;

    k_transpose<<<dim3(1152 + 28), dim3(256), 0, stream>>>(x, xt16, offw, mw, convw, wfm, wfo, wz);
    k_fused    <<<dim3(1152),      dim3(256), 0, stream>>>(xt16, wfo, wfm, offb, mb, convb, wz, out);
}

// Round 7
// 113.262 us; speedup vs baseline: 1.3357x; 1.0217x over previous
//
#include <hip/hip_runtime.h>
#include <hip/hip_fp16.h>
#include <cstddef>

#define B_   8
#define H_   96
#define W_   96
#define HW_  9216
#define PIX_ 73728

// LDS window geometry: rows hr-2..hr+3 (6), cols wc-3..wc+34 (38)
#define NWR    6
#define NWC    38
#define WINPX  228
#define NSLOTS 19

typedef __attribute__((ext_vector_type(8))) _Float16 halfx8;
typedef __attribute__((ext_vector_type(2))) __fp16 fp16x2_raw;
typedef __attribute__((ext_vector_type(4))) float floatx4;

// ws layout (byte offsets)
#define XT_OFF   0                          // fp16 NHWC x: PIX*64*2
#define WFM_OFF  (XT_OFF + PIX_*64*2)       // main W frags: 18*4*64*8 fp16
#define WFO_OFF  (WFM_OFF + 18*4*64*8*2)    // offs W frags: 18*2*64*8 fp16
#define WZ_OFF   (WFO_OFF + 18*2*64*8*2)    // 128B zero page

__device__ __forceinline__ unsigned pk2h(float a, float b) {
    fp16x2_raw h = __builtin_amdgcn_cvt_pkrtz(a, b);
    union { fp16x2_raw h2; unsigned u; } t; t.h2 = h; return t.u;
}
__device__ __forceinline__ halfx8 uph8(uint4 u) {
    union { uint4 u4; halfx8 h; } t; t.u4 = u; return t.h;
}
__device__ __forceinline__ halfx8 splat8(unsigned d) {
    union { unsigned u[4]; halfx8 h; } t;
    t.u[0] = d; t.u[1] = d; t.u[2] = d; t.u[3] = d; return t.h;
}
__device__ __forceinline__ void async_ld16(const void* g, void* l) {
    __builtin_amdgcn_global_load_lds((const __attribute__((address_space(1))) void*)g,
                                     (__attribute__((address_space(3))) void*)l,
                                     16, 0, 0);
}

// ---------------------------------------------------------------------------
// NCHW f32 -> NHWC fp16 transpose via LDS tile; tail blocks pack weights.
__global__ __launch_bounds__(256) void k_transpose(const float* __restrict__ x,
                                                   unsigned short* __restrict__ xt,
                                                   const float* __restrict__ offw,
                                                   const float* __restrict__ mw,
                                                   const float* __restrict__ convw,
                                                   unsigned short* __restrict__ wfm,
                                                   unsigned short* __restrict__ wfo,
                                                   unsigned short* __restrict__ wz) {
    if (blockIdx.x >= 1152) {
        // ---- weight-prep branch (28 blocks) ----
        int g = (blockIdx.x - 1152) * 256 + threadIdx.x;
        if (g < 4608) {
            int lane = g & 63, mtks = g >> 6;
            int mt = mtks & 3, ks = mtks >> 2;
            int o = mt * 16 + (lane & 15), quad = lane >> 4;
            float v[8];
            #pragma unroll
            for (int j = 0; j < 8; ++j) {
                int k = ks * 32 + quad * 8 + j;
                int t = k / 64, c = k % 64;
                v[j] = convw[(size_t)(o * 64 + c) * 9 + t];
            }
            uint4 pk;
            pk.x = pk2h(v[0], v[1]); pk.y = pk2h(v[2], v[3]);
            pk.z = pk2h(v[4], v[5]); pk.w = pk2h(v[6], v[7]);
            *(uint4*)(wfm + (size_t)g * 8) = pk;
        } else if (g < 4608 + 2304) {
            int g2 = g - 4608;
            int lane = g2 & 63, mtks = g2 >> 6;
            int mt = mtks & 1, ks = mtks >> 1;
            int m = mt * 16 + (lane & 15), quad = lane >> 4;
            float v[8];
            #pragma unroll
            for (int j = 0; j < 8; ++j) {
                int k = ks * 32 + quad * 8 + j;
                int t = k / 64, c = k % 64;
                float f = 0.f;
                if (m < 18)      f = offw[(size_t)(m * 64 + c) * 9 + t];
                else if (m < 27) f = mw[(size_t)((m - 18) * 64 + c) * 9 + t];
                v[j] = f;
            }
            uint4 pk;
            pk.x = pk2h(v[0], v[1]); pk.y = pk2h(v[2], v[3]);
            pk.z = pk2h(v[4], v[5]); pk.w = pk2h(v[6], v[7]);
            *(uint4*)(wfo + (size_t)g2 * 8) = pk;
        } else if (g < 4608 + 2304 + 8) {
            // zero page (128 B)
            uint4 z = make_uint4(0, 0, 0, 0);
            *(uint4*)(wz + (size_t)(g - 6912) * 8) = z;
        }
        return;
    }

    __shared__ float tile[64 * 65];
    int bb  = blockIdx.x / 144;
    int sp0 = (blockIdx.x % 144) * 64;
    int t = threadIdx.x;
    int s4 = (t & 15) * 4, cq = t >> 4;
    #pragma unroll
    for (int i = 0; i < 4; ++i) {
        int c = cq + 16 * i;
        float4 v = *(const float4*)&x[(size_t)(bb * 64 + c) * HW_ + sp0 + s4];
        tile[c * 65 + s4 + 0] = v.x;
        tile[c * 65 + s4 + 1] = v.y;
        tile[c * 65 + s4 + 2] = v.z;
        tile[c * 65 + s4 + 3] = v.w;
    }
    __syncthreads();
    // each lane packs 8 channels of one pixel -> 1KB contiguous per wave-store
    int c8 = t & 7, sgrp = t >> 3;      // sgrp 0..31
    #pragma unroll
    for (int i = 0; i < 2; ++i) {
        int s2 = i * 32 + sgrp;
        uint4 pk;
        pk.x = pk2h(tile[(c8 * 8 + 0) * 65 + s2], tile[(c8 * 8 + 1) * 65 + s2]);
        pk.y = pk2h(tile[(c8 * 8 + 2) * 65 + s2], tile[(c8 * 8 + 3) * 65 + s2]);
        pk.z = pk2h(tile[(c8 * 8 + 4) * 65 + s2], tile[(c8 * 8 + 5) * 65 + s2]);
        pk.w = pk2h(tile[(c8 * 8 + 6) * 65 + s2], tile[(c8 * 8 + 7) * 65 + s2]);
        *(uint4*)(xt + (size_t)(bb * HW_ + sp0 + s2) * 64 + c8 * 8) = pk;
    }
}

// ---------------------------------------------------------------------------
// Fused kernel. Block = 256 thr = 4 waves, owns 64 px (2 rows x 32 cols).
// 6x38 window DMA'd into LDS (swizzle folded into source; OOB -> zero page).
// s_off aliased onto s_meta (union). LDS ~39.9 KB -> 4 blocks/CU.
__global__ __launch_bounds__(256, 4) void k_fused(const unsigned short* __restrict__ xt,
                                                  const unsigned short* __restrict__ wfo,
                                                  const unsigned short* __restrict__ wfm,
                                                  const float* __restrict__ offb,
                                                  const float* __restrict__ mb,
                                                  const float* __restrict__ convb,
                                                  const unsigned short* __restrict__ wz,
                                                  float* __restrict__ out) {
    __shared__ __align__(16) unsigned char s_win[(WINPX + NSLOTS) * 128];  // 31616 B
    __shared__ __align__(16) unsigned char s_u[9216];                      // union: s_off then s_meta
    __shared__ int s_cnt;
    float* s_off = (float*)s_u;            // 27 x 66 f32 (phase 1-2)
    unsigned char* s_meta = s_u;           // 64 x 9 x 16 B (phase 2-3)

    int tid = threadIdx.x;
    int w = tid >> 6, lane = tid & 63, col = lane & 15, quad = lane >> 4;
    // XCD-aware swizzle: each XCD gets one batch's 144 contiguous tiles
    int blk = (blockIdx.x & 7) * 144 + (blockIdx.x >> 3);
    int bb  = blk / 144;
    int rem = blk % 144;
    int hr  = (rem / 3) * 2;            // top row of the 2-row tile
    int wc  = (rem % 3) * 32;           // left col of the 32-col segment
    const unsigned short* xtb = xt + (size_t)bb * HW_ * 64;

    // ---- stage window: direct-to-LDS DMA, source pre-swizzled; OOB -> zeros ----
    if (tid == 0) s_cnt = 0;
    {
        int p0  = lane >> 3;                    // pixel-within-group
        int cgx = (lane & 7) ^ p0;              // swizzled source ch-group
        const unsigned short* wzp = wz + cgx * 8;
        for (int i = w; i < 29; i += 4) {       // 29 groups of 8 px, split by wave
            int p = i * 8 + p0;
            int wr = p / NWC, wcl = p - wr * NWC;
            int gr = hr - 2 + wr, gc = wc - 3 + wcl;
            bool ok = (p < WINPX) && ((unsigned)gr < 96u) && ((unsigned)gc < 96u);
            const unsigned short* src = ok ? (xtb + ((size_t)(gr * 96 + gc) * 64 + cgx * 8)) : wzp;
            async_ld16(src, s_win + i * 1024);
        }
    }
    __syncthreads();

    // ---- phase 1: offset/mod conv GEMM (B from LDS window) ----
    floatx4 aoff0 = (floatx4){0.f, 0.f, 0.f, 0.f};
    floatx4 aoff1 = (floatx4){0.f, 0.f, 0.f, 0.f};
    {
        int wr_base = 2 + (w >> 1);
        int wc_base = 3 + (w & 1) * 16 + col;
        #pragma unroll
        for (int t = 0; t < 9; ++t) {
            int dh = t / 3 - 1, dw = t % 3 - 1;
            int p = (wr_base + dh) * NWC + (wc_base + dw);
            int pb = p << 7, psw = (p & 7) << 4;
            #pragma unroll
            for (int ksl = 0; ksl < 2; ++ksl) {
                int ks = t * 2 + ksl;
                halfx8 a0 = *(const halfx8*)(wfo + ((size_t)(ks * 2 + 0) * 64 + lane) * 8);
                halfx8 a1 = *(const halfx8*)(wfo + ((size_t)(ks * 2 + 1) * 64 + lane) * 8);
                uint4 bvu = *(const uint4*)(s_win + pb + ((quad * 16 + ksl * 64) ^ psw));
                halfx8 bv = uph8(bvu);
                aoff0 = __builtin_amdgcn_mfma_f32_16x16x32_f16(a0, bv, aoff0, 0, 0, 0);
                aoff1 = __builtin_amdgcn_mfma_f32_16x16x32_f16(a1, bv, aoff1, 0, 0, 0);
            }
        }
    }
    #pragma unroll
    for (int r = 0; r < 4; ++r) {
        s_off[(quad * 4 + r) * 66 + (w * 16 + col)] = aoff0[r];
        int m = 16 + quad * 4 + r;
        if (m < 27) s_off[m * 66 + (w * 16 + col)] = aoff1[r];
    }
    __syncthreads();

    // ---- phase 2a: read s_off (+bias) into static registers ----
    float ox0, oy0, mv0, ox1, oy1, mv1, ox2 = 0.f, oy2 = 0.f, mv2 = 0.f;
    bool has2 = (tid + 512) < 576;
    {
        int px = tid & 63, n = tid >> 6;
        ox0 = s_off[n * 66 + px]        + offb[n];
        oy0 = s_off[(9 + n) * 66 + px]  + offb[9 + n];
        mv0 = s_off[(18 + n) * 66 + px] + mb[n];
    }
    {
        int id = tid + 256;
        int px = id & 63, n = id >> 6;
        ox1 = s_off[n * 66 + px]        + offb[n];
        oy1 = s_off[(9 + n) * 66 + px]  + offb[9 + n];
        mv1 = s_off[(18 + n) * 66 + px] + mb[n];
    }
    if (has2) {
        int id = tid + 512;
        int px = id & 63, n = id >> 6;
        ox2 = s_off[n * 66 + px]        + offb[n];
        oy2 = s_off[(9 + n) * 66 + px]  + offb[9 + n];
        mv2 = s_off[(18 + n) * 66 + px] + mb[n];
    }
    __syncthreads();   // s_off fully read; s_u becomes s_meta

    // ---- phase 2b: bilinear metadata (s_meta aliases s_off's space) ----
    auto meta_one = [&](int id, float ox, float oy, float mv) {
        int px = id & 63, n = id >> 6;
        float modv = 1.f / (1.f + __expf(-mv));
        int prow = hr + (px >> 5), pcol = wc + (px & 31);
        float pxx = ox + (float)(prow + 1) + (float)(n / 3 - 1);
        float pyy = oy + (float)(pcol + 1) + (float)(n % 3 - 1);
        float flx = floorf(pxx), fly = floorf(pyy);
        float tlxf = fminf(fmaxf(flx,       0.f), 97.f);
        float tlyf = fminf(fmaxf(fly,       0.f), 97.f);
        float brxf = fminf(fmaxf(flx + 1.f, 0.f), 97.f);
        float bryf = fminf(fmaxf(fly + 1.f, 0.f), 97.f);
        float pcx  = fminf(fmaxf(pxx, 0.f), 97.f);
        float pcy  = fminf(fmaxf(pyy, 0.f), 97.f);
        float gx0 = 1.f + tlxf - pcx;
        float gx1 = 1.f - (brxf - pcx);
        float gy0 = 1.f + tlyf - pcy;
        float gy1 = 1.f - (bryf - pcy);
        int tlx = (int)tlxf, tly = (int)tlyf, brx = (int)brxf, bry = (int)bryf;
        int   qxs[4] = {tlx, tlx, brx, brx};
        int   qys[4] = {tly, bry, tly, bry};
        float gs4[4] = {gx0 * gy0, gx0 * gy1, gx1 * gy0, gx1 * gy1};
        unsigned short si[4]; unsigned short hg[4];
        #pragma unroll
        for (int c4 = 0; c4 < 4; ++c4) {
            int qx = qxs[c4], qy = qys[c4];
            bool valid = (qx >= 1) && (qx <= 96) && (qy >= 1) && (qy <= 96);
            int gr = qx - 1, gc = qy - 1;
            int wr = gr - (hr - 2), wcl = gc - (wc - 3);
            bool inwin = ((unsigned)wr < (unsigned)NWR) && ((unsigned)wcl < (unsigned)NWC);
            unsigned short idxv; float gvf;
            if (inwin) {
                idxv = (unsigned short)(wr * NWC + wcl);   // zeros staged for out-of-image
                gvf = gs4[c4] * modv;
            } else if (!valid) {
                idxv = 0; gvf = 0.f;
            } else {
                // rare: valid corner outside window -> copy into LDS overflow slot
                int s = atomicAdd(&s_cnt, 1);
                int gidx = gr * 96 + gc;
                if (s < NSLOTS) {
                    int ps = WINPX + s;
                    #pragma unroll
                    for (int ch = 0; ch < 8; ++ch) {
                        uint4 v = *(const uint4*)(xtb + (size_t)gidx * 64 + ch * 8);
                        *(uint4*)(s_win + (size_t)ps * 128 + ((ch ^ (ps & 7)) * 16)) = v;
                    }
                    idxv = (unsigned short)ps;
                } else {
                    idxv = (unsigned short)(0x8000u | (unsigned)gidx);  // global fallback tag
                }
                gvf = gs4[c4] * modv;
            }
            si[c4] = idxv;
            hg[c4] = __half_as_ushort(__float2half_rn(gvf));
        }
        uint4 mw4;
        mw4.x = si[0] | ((unsigned)si[1] << 16);
        mw4.y = si[2] | ((unsigned)si[3] << 16);
        mw4.z = hg[0] | ((unsigned)hg[1] << 16);
        mw4.w = hg[2] | ((unsigned)hg[3] << 16);
        *(uint4*)(s_meta + ((size_t)px * 9 + n) * 16) = mw4;
    };
    meta_one(tid,       ox0, oy0, mv0);
    meta_one(tid + 256, ox1, oy1, mv1);
    if (has2) meta_one(tid + 512, ox2, oy2, mv2);
    __syncthreads();

    // ---- phase 3: main contraction; packed-fp16 combine ----
    int mth = w & 1, pg = w >> 1;      // wave: o-half mth, px-half pg
    floatx4 acc[2][2];
    #pragma unroll
    for (int jj = 0; jj < 2; ++jj)
        #pragma unroll
        for (int mtl = 0; mtl < 2; ++mtl) acc[jj][mtl] = (floatx4){0.f, 0.f, 0.f, 0.f};

    int qk0 = quad * 16, qk1 = quad * 16 + 64;

    #pragma unroll
    for (int n = 0; n < 9; ++n) {
        halfx8 af00 = *(const halfx8*)(wfm + ((size_t)((n * 2 + 0) * 4 + mth * 2 + 0) * 64 + lane) * 8);
        halfx8 af01 = *(const halfx8*)(wfm + ((size_t)((n * 2 + 0) * 4 + mth * 2 + 1) * 64 + lane) * 8);
        halfx8 af10 = *(const halfx8*)(wfm + ((size_t)((n * 2 + 1) * 4 + mth * 2 + 0) * 64 + lane) * 8);
        halfx8 af11 = *(const halfx8*)(wfm + ((size_t)((n * 2 + 1) * 4 + mth * 2 + 1) * 64 + lane) * 8);
        #pragma unroll
        for (int jj = 0; jj < 2; ++jj) {
            int px = pg * 32 + jj * 16 + col;
            uint4 mu = *(const uint4*)(s_meta + ((size_t)px * 9 + n) * 16);
            unsigned i0 = mu.x & 0xFFFFu, i1 = mu.x >> 16;
            unsigned i2 = mu.y & 0xFFFFu, i3 = mu.y >> 16;
            int pm0 = (i0 & 0x8000u) ? 0 : (int)i0;
            int pm1 = (i1 & 0x8000u) ? 0 : (int)i1;
            int pm2 = (i2 & 0x8000u) ? 0 : (int)i2;
            int pm3 = (i3 & 0x8000u) ? 0 : (int)i3;
            int b0 = pm0 << 7, s0 = (pm0 & 7) << 4;
            int b1 = pm1 << 7, s1 = (pm1 & 7) << 4;
            int b2 = pm2 << 7, s2 = (pm2 & 7) << 4;
            int b3 = pm3 << 7, s3 = (pm3 & 7) << 4;
            uint4 cA0 = *(const uint4*)(s_win + b0 + (qk0 ^ s0));
            uint4 cA1 = *(const uint4*)(s_win + b1 + (qk0 ^ s1));
            uint4 cA2 = *(const uint4*)(s_win + b2 + (qk0 ^ s2));
            uint4 cA3 = *(const uint4*)(s_win + b3 + (qk0 ^ s3));
            uint4 cB0 = *(const uint4*)(s_win + b0 + (qk1 ^ s0));
            uint4 cB1 = *(const uint4*)(s_win + b1 + (qk1 ^ s1));
            uint4 cB2 = *(const uint4*)(s_win + b2 + (qk1 ^ s2));
            uint4 cB3 = *(const uint4*)(s_win + b3 + (qk1 ^ s3));
            if (__any((int)((i0 | i1 | i2 | i3) & 0x8000u))) {
                // ultra-rare global fallback (slot overflow)
                if (i0 & 0x8000u) { size_t ga = (size_t)(i0 & 0x3FFFu) * 64 + quad * 8;
                    cA0 = *(const uint4*)(xtb + ga); cB0 = *(const uint4*)(xtb + ga + 32); }
                if (i1 & 0x8000u) { size_t ga = (size_t)(i1 & 0x3FFFu) * 64 + quad * 8;
                    cA1 = *(const uint4*)(xtb + ga); cB1 = *(const uint4*)(xtb + ga + 32); }
                if (i2 & 0x8000u) { size_t ga = (size_t)(i2 & 0x3FFFu) * 64 + quad * 8;
                    cA2 = *(const uint4*)(xtb + ga); cB2 = *(const uint4*)(xtb + ga + 32); }
                if (i3 & 0x8000u) { size_t ga = (size_t)(i3 & 0x3FFFu) * 64 + quad * 8;
                    cA3 = *(const uint4*)(xtb + ga); cB3 = *(const uint4*)(xtb + ga + 32); }
            }
            // splat each half g to a packed pair, then pure v_pk_mul/fma_f16
            unsigned gl0 = (mu.z & 0xFFFFu) | (mu.z << 16);
            unsigned gl1 = (mu.z >> 16) | (mu.z & 0xFFFF0000u);
            unsigned gl2 = (mu.w & 0xFFFFu) | (mu.w << 16);
            unsigned gl3 = (mu.w >> 16) | (mu.w & 0xFFFF0000u);
            halfx8 g0 = splat8(gl0), g1 = splat8(gl1), g2 = splat8(gl2), g3 = splat8(gl3);
            halfx8 vA = uph8(cA0) * g0;
            vA += uph8(cA1) * g1; vA += uph8(cA2) * g2; vA += uph8(cA3) * g3;
            halfx8 vB = uph8(cB0) * g0;
            vB += uph8(cB1) * g1; vB += uph8(cB2) * g2; vB += uph8(cB3) * g3;
            acc[jj][0] = __builtin_amdgcn_mfma_f32_16x16x32_f16(af00, vA, acc[jj][0], 0, 0, 0);
            acc[jj][1] = __builtin_amdgcn_mfma_f32_16x16x32_f16(af01, vA, acc[jj][1], 0, 0, 0);
            acc[jj][0] = __builtin_amdgcn_mfma_f32_16x16x32_f16(af10, vB, acc[jj][0], 0, 0, 0);
            acc[jj][1] = __builtin_amdgcn_mfma_f32_16x16x32_f16(af11, vB, acc[jj][1], 0, 0, 0);
        }
    }

    // ---- epilogue ----
    int prow = hr + pg;
    #pragma unroll
    for (int mtl = 0; mtl < 2; ++mtl) {
        float4 cb4 = *(const float4*)&convb[mth * 32 + mtl * 16 + quad * 4];
        #pragma unroll
        for (int jj = 0; jj < 2; ++jj) {
            int sp = prow * 96 + wc + jj * 16 + col;
            #pragma unroll
            for (int r = 0; r < 4; ++r) {
                int o = mth * 32 + mtl * 16 + quad * 4 + r;
                float bias = (r == 0) ? cb4.x : (r == 1) ? cb4.y : (r == 2) ? cb4.z : cb4.w;
                out[(size_t)(bb * 64 + o) * HW_ + sp] = acc[jj][mtl][r] + bias;
            }
        }
    }
}

// ---------------------------------------------------------------------------
extern "C" void kernel_launch(void* const* d_in, const int* in_sizes, int n_in,
                              void* d_out, int out_size, void* d_ws, size_t ws_size,
                              hipStream_t stream) {
    const float* x     = (const float*)d_in[0];
    const float* offw  = (const float*)d_in[1];
    const float* offb  = (const float*)d_in[2];
    const float* mw    = (const float*)d_in[3];
    const float* mb    = (const float*)d_in[4];
    const float* convw = (const float*)d_in[5];
    const float* convb = (const float*)d_in[6];
    char* ws = (char*)d_ws;
    unsigned short* xt16 = (unsigned short*)(ws + XT_OFF);
    unsigned short* wfm  = (unsigned short*)(ws + WFM_OFF);
    unsigned short* wfo  = (unsigned short*)(ws + WFO_OFF);
    unsigned short* wz   = (unsigned short*)(ws + WZ_OFF);
    float* out = (float*)d_out;

    k_transpose<<<dim3(1152 + 28), dim3(256), 0, stream>>>(x, xt16, offw, mw, convw, wfm, wfo, wz);
    k_fused    <<<dim3(1152),      dim3(256), 0, stream>>>(xt16, wfo, wfm, offb, mb, convb, wz, out);
}

// Round 8
// 109.632 us; speedup vs baseline: 1.3799x; 1.0331x over previous
//
#include <hip/hip_runtime.h>
#include <hip/hip_fp16.h>
#include <cstddef>

#define B_   8
#define H_   96
#define W_   96
#define HW_  9216
#define PIX_ 73728

// LDS window geometry: rows hr-2..hr+3 (6), cols wc-3..wc+34 (38)
#define NWR    6
#define NWC    38
#define WINPX  228
#define NSLOTS 19

typedef __attribute__((ext_vector_type(8))) _Float16 halfx8;
typedef __attribute__((ext_vector_type(2))) __fp16 fp16x2_raw;
typedef __attribute__((ext_vector_type(4))) float floatx4;

// ws layout (byte offsets)
#define XT_OFF   0                          // fp16 NHWC x: PIX*64*2
#define WFM_OFF  (XT_OFF + PIX_*64*2)       // main W frags: 18*4*64*8 fp16
#define WFO_OFF  (WFM_OFF + 18*4*64*8*2)    // offs W frags: 18*2*64*8 fp16
#define WZ_OFF   (WFO_OFF + 18*2*64*8*2)    // 128B zero page

__device__ __forceinline__ unsigned pk2h(float a, float b) {
    fp16x2_raw h = __builtin_amdgcn_cvt_pkrtz(a, b);
    union { fp16x2_raw h2; unsigned u; } t; t.h2 = h; return t.u;
}
__device__ __forceinline__ halfx8 uph8(uint4 u) {
    union { uint4 u4; halfx8 h; } t; t.u4 = u; return t.h;
}
__device__ __forceinline__ halfx8 splat8(unsigned d) {
    union { unsigned u[4]; halfx8 h; } t;
    t.u[0] = d; t.u[1] = d; t.u[2] = d; t.u[3] = d; return t.h;
}
__device__ __forceinline__ void async_ld16(const void* g, void* l) {
    __builtin_amdgcn_global_load_lds((const __attribute__((address_space(1))) void*)g,
                                     (__attribute__((address_space(3))) void*)l,
                                     16, 0, 0);
}

// ---------------------------------------------------------------------------
// NCHW f32 -> NHWC fp16 transpose via LDS tile; tail blocks pack weights.
__global__ __launch_bounds__(256) void k_transpose(const float* __restrict__ x,
                                                   unsigned short* __restrict__ xt,
                                                   const float* __restrict__ offw,
                                                   const float* __restrict__ mw,
                                                   const float* __restrict__ convw,
                                                   unsigned short* __restrict__ wfm,
                                                   unsigned short* __restrict__ wfo,
                                                   unsigned short* __restrict__ wz) {
    if (blockIdx.x >= 1152) {
        // ---- weight-prep branch (28 blocks) ----
        int g = (blockIdx.x - 1152) * 256 + threadIdx.x;
        if (g < 4608) {
            int lane = g & 63, mtks = g >> 6;
            int mt = mtks & 3, ks = mtks >> 2;
            int o = mt * 16 + (lane & 15), quad = lane >> 4;
            float v[8];
            #pragma unroll
            for (int j = 0; j < 8; ++j) {
                int k = ks * 32 + quad * 8 + j;
                int t = k / 64, c = k % 64;
                v[j] = convw[(size_t)(o * 64 + c) * 9 + t];
            }
            uint4 pk;
            pk.x = pk2h(v[0], v[1]); pk.y = pk2h(v[2], v[3]);
            pk.z = pk2h(v[4], v[5]); pk.w = pk2h(v[6], v[7]);
            *(uint4*)(wfm + (size_t)g * 8) = pk;
        } else if (g < 4608 + 2304) {
            int g2 = g - 4608;
            int lane = g2 & 63, mtks = g2 >> 6;
            int mt = mtks & 1, ks = mtks >> 1;
            int m = mt * 16 + (lane & 15), quad = lane >> 4;
            float v[8];
            #pragma unroll
            for (int j = 0; j < 8; ++j) {
                int k = ks * 32 + quad * 8 + j;
                int t = k / 64, c = k % 64;
                float f = 0.f;
                if (m < 18)      f = offw[(size_t)(m * 64 + c) * 9 + t];
                else if (m < 27) f = mw[(size_t)((m - 18) * 64 + c) * 9 + t];
                v[j] = f;
            }
            uint4 pk;
            pk.x = pk2h(v[0], v[1]); pk.y = pk2h(v[2], v[3]);
            pk.z = pk2h(v[4], v[5]); pk.w = pk2h(v[6], v[7]);
            *(uint4*)(wfo + (size_t)g2 * 8) = pk;
        } else if (g < 4608 + 2304 + 8) {
            // zero page (128 B)
            uint4 z = make_uint4(0, 0, 0, 0);
            *(uint4*)(wz + (size_t)(g - 6912) * 8) = z;
        }
        return;
    }

    __shared__ float tile[64 * 65];
    int bb  = blockIdx.x / 144;
    int sp0 = (blockIdx.x % 144) * 64;
    int t = threadIdx.x;
    int s4 = (t & 15) * 4, cq = t >> 4;
    #pragma unroll
    for (int i = 0; i < 4; ++i) {
        int c = cq + 16 * i;
        float4 v = *(const float4*)&x[(size_t)(bb * 64 + c) * HW_ + sp0 + s4];
        tile[c * 65 + s4 + 0] = v.x;
        tile[c * 65 + s4 + 1] = v.y;
        tile[c * 65 + s4 + 2] = v.z;
        tile[c * 65 + s4 + 3] = v.w;
    }
    __syncthreads();
    // each lane packs 8 channels of one pixel -> 1KB contiguous per wave-store
    int c8 = t & 7, sgrp = t >> 3;      // sgrp 0..31
    #pragma unroll
    for (int i = 0; i < 2; ++i) {
        int s2 = i * 32 + sgrp;
        uint4 pk;
        pk.x = pk2h(tile[(c8 * 8 + 0) * 65 + s2], tile[(c8 * 8 + 1) * 65 + s2]);
        pk.y = pk2h(tile[(c8 * 8 + 2) * 65 + s2], tile[(c8 * 8 + 3) * 65 + s2]);
        pk.z = pk2h(tile[(c8 * 8 + 4) * 65 + s2], tile[(c8 * 8 + 5) * 65 + s2]);
        pk.w = pk2h(tile[(c8 * 8 + 6) * 65 + s2], tile[(c8 * 8 + 7) * 65 + s2]);
        *(uint4*)(xt + (size_t)(bb * HW_ + sp0 + s2) * 64 + c8 * 8) = pk;
    }
}

// ---------------------------------------------------------------------------
// Fused kernel. Block = 256 thr = 4 waves, owns 64 px (2 rows x 32 cols).
// 6x38 window DMA'd into LDS; s_off aliased onto s_meta. 4 blocks/CU.
// Phase 3: wave = 16 px x ALL 64 o-channels (no duplicate gather/combine).
__global__ __launch_bounds__(256, 4) void k_fused(const unsigned short* __restrict__ xt,
                                                  const unsigned short* __restrict__ wfo,
                                                  const unsigned short* __restrict__ wfm,
                                                  const float* __restrict__ offb,
                                                  const float* __restrict__ mb,
                                                  const float* __restrict__ convb,
                                                  const unsigned short* __restrict__ wz,
                                                  float* __restrict__ out) {
    __shared__ __align__(16) unsigned char s_win[(WINPX + NSLOTS) * 128];  // 31616 B
    __shared__ __align__(16) unsigned char s_u[9216];                      // union: s_off then s_meta
    __shared__ int s_cnt;
    float* s_off = (float*)s_u;            // 27 x 66 f32 (phase 1-2)
    unsigned char* s_meta = s_u;           // 64 x 9 x 16 B (phase 2-3)

    int tid = threadIdx.x;
    int w = tid >> 6, lane = tid & 63, col = lane & 15, quad = lane >> 4;
    // XCD-aware swizzle: each XCD gets one batch's 144 contiguous tiles
    int blk = (blockIdx.x & 7) * 144 + (blockIdx.x >> 3);
    int bb  = blk / 144;
    int rem = blk % 144;
    int hr  = (rem / 3) * 2;            // top row of the 2-row tile
    int wc  = (rem % 3) * 32;           // left col of the 32-col segment
    const unsigned short* xtb = xt + (size_t)bb * HW_ * 64;

    // ---- stage window: direct-to-LDS DMA, source pre-swizzled; OOB -> zeros ----
    if (tid == 0) s_cnt = 0;
    {
        int p0  = lane >> 3;                    // pixel-within-group
        int cgx = (lane & 7) ^ p0;              // swizzled source ch-group
        const unsigned short* wzp = wz + cgx * 8;
        for (int i = w; i < 29; i += 4) {       // 29 groups of 8 px, split by wave
            int p = i * 8 + p0;
            int wr = p / NWC, wcl = p - wr * NWC;
            int gr = hr - 2 + wr, gc = wc - 3 + wcl;
            bool ok = (p < WINPX) && ((unsigned)gr < 96u) && ((unsigned)gc < 96u);
            const unsigned short* src = ok ? (xtb + ((size_t)(gr * 96 + gc) * 64 + cgx * 8)) : wzp;
            async_ld16(src, s_win + i * 1024);
        }
    }
    __syncthreads();

    // ---- phase 1: offset/mod conv GEMM (B from LDS window) ----
    floatx4 aoff0 = (floatx4){0.f, 0.f, 0.f, 0.f};
    floatx4 aoff1 = (floatx4){0.f, 0.f, 0.f, 0.f};
    {
        int wr_base = 2 + (w >> 1);
        int wc_base = 3 + (w & 1) * 16 + col;
        #pragma unroll
        for (int t = 0; t < 9; ++t) {
            int dh = t / 3 - 1, dw = t % 3 - 1;
            int p = (wr_base + dh) * NWC + (wc_base + dw);
            int pb = p << 7, psw = (p & 7) << 4;
            #pragma unroll
            for (int ksl = 0; ksl < 2; ++ksl) {
                int ks = t * 2 + ksl;
                halfx8 a0 = *(const halfx8*)(wfo + ((size_t)(ks * 2 + 0) * 64 + lane) * 8);
                halfx8 a1 = *(const halfx8*)(wfo + ((size_t)(ks * 2 + 1) * 64 + lane) * 8);
                uint4 bvu = *(const uint4*)(s_win + pb + ((quad * 16 + ksl * 64) ^ psw));
                halfx8 bv = uph8(bvu);
                aoff0 = __builtin_amdgcn_mfma_f32_16x16x32_f16(a0, bv, aoff0, 0, 0, 0);
                aoff1 = __builtin_amdgcn_mfma_f32_16x16x32_f16(a1, bv, aoff1, 0, 0, 0);
            }
        }
    }
    #pragma unroll
    for (int r = 0; r < 4; ++r) {
        s_off[(quad * 4 + r) * 66 + (w * 16 + col)] = aoff0[r];
        int m = 16 + quad * 4 + r;
        if (m < 27) s_off[m * 66 + (w * 16 + col)] = aoff1[r];
    }
    __syncthreads();

    // ---- phase 2a: read s_off (+bias) into static registers ----
    float ox0, oy0, mv0, ox1, oy1, mv1, ox2 = 0.f, oy2 = 0.f, mv2 = 0.f;
    bool has2 = (tid + 512) < 576;
    {
        int px = tid & 63, n = tid >> 6;
        ox0 = s_off[n * 66 + px]        + offb[n];
        oy0 = s_off[(9 + n) * 66 + px]  + offb[9 + n];
        mv0 = s_off[(18 + n) * 66 + px] + mb[n];
    }
    {
        int id = tid + 256;
        int px = id & 63, n = id >> 6;
        ox1 = s_off[n * 66 + px]        + offb[n];
        oy1 = s_off[(9 + n) * 66 + px]  + offb[9 + n];
        mv1 = s_off[(18 + n) * 66 + px] + mb[n];
    }
    if (has2) {
        int id = tid + 512;
        int px = id & 63, n = id >> 6;
        ox2 = s_off[n * 66 + px]        + offb[n];
        oy2 = s_off[(9 + n) * 66 + px]  + offb[9 + n];
        mv2 = s_off[(18 + n) * 66 + px] + mb[n];
    }
    __syncthreads();   // s_off fully read; s_u becomes s_meta

    // ---- phase 2b: bilinear metadata (s_meta aliases s_off's space) ----
    auto meta_one = [&](int id, float ox, float oy, float mv) {
        int px = id & 63, n = id >> 6;
        float modv = 1.f / (1.f + __expf(-mv));
        int prow = hr + (px >> 5), pcol = wc + (px & 31);
        float pxx = ox + (float)(prow + 1) + (float)(n / 3 - 1);
        float pyy = oy + (float)(pcol + 1) + (float)(n % 3 - 1);
        float flx = floorf(pxx), fly = floorf(pyy);
        float tlxf = fminf(fmaxf(flx,       0.f), 97.f);
        float tlyf = fminf(fmaxf(fly,       0.f), 97.f);
        float brxf = fminf(fmaxf(flx + 1.f, 0.f), 97.f);
        float bryf = fminf(fmaxf(fly + 1.f, 0.f), 97.f);
        float pcx  = fminf(fmaxf(pxx, 0.f), 97.f);
        float pcy  = fminf(fmaxf(pyy, 0.f), 97.f);
        float gx0 = 1.f + tlxf - pcx;
        float gx1 = 1.f - (brxf - pcx);
        float gy0 = 1.f + tlyf - pcy;
        float gy1 = 1.f - (bryf - pcy);
        int tlx = (int)tlxf, tly = (int)tlyf, brx = (int)brxf, bry = (int)bryf;
        int   qxs[4] = {tlx, tlx, brx, brx};
        int   qys[4] = {tly, bry, tly, bry};
        float gs4[4] = {gx0 * gy0, gx0 * gy1, gx1 * gy0, gx1 * gy1};
        unsigned short si[4]; unsigned short hg[4];
        #pragma unroll
        for (int c4 = 0; c4 < 4; ++c4) {
            int qx = qxs[c4], qy = qys[c4];
            bool valid = (qx >= 1) && (qx <= 96) && (qy >= 1) && (qy <= 96);
            int gr = qx - 1, gc = qy - 1;
            int wr = gr - (hr - 2), wcl = gc - (wc - 3);
            bool inwin = ((unsigned)wr < (unsigned)NWR) && ((unsigned)wcl < (unsigned)NWC);
            unsigned short idxv; float gvf;
            if (inwin) {
                idxv = (unsigned short)(wr * NWC + wcl);   // zeros staged for out-of-image
                gvf = gs4[c4] * modv;
            } else if (!valid) {
                idxv = 0; gvf = 0.f;
            } else {
                // rare: valid corner outside window -> copy into LDS overflow slot
                int s = atomicAdd(&s_cnt, 1);
                int gidx = gr * 96 + gc;
                if (s < NSLOTS) {
                    int ps = WINPX + s;
                    #pragma unroll
                    for (int ch = 0; ch < 8; ++ch) {
                        uint4 v = *(const uint4*)(xtb + (size_t)gidx * 64 + ch * 8);
                        *(uint4*)(s_win + (size_t)ps * 128 + ((ch ^ (ps & 7)) * 16)) = v;
                    }
                    idxv = (unsigned short)ps;
                } else {
                    idxv = (unsigned short)(0x8000u | (unsigned)gidx);  // global fallback tag
                }
                gvf = gs4[c4] * modv;
            }
            si[c4] = idxv;
            hg[c4] = __half_as_ushort(__float2half_rn(gvf));
        }
        uint4 mw4;
        mw4.x = si[0] | ((unsigned)si[1] << 16);
        mw4.y = si[2] | ((unsigned)si[3] << 16);
        mw4.z = hg[0] | ((unsigned)hg[1] << 16);
        mw4.w = hg[2] | ((unsigned)hg[3] << 16);
        *(uint4*)(s_meta + ((size_t)px * 9 + n) * 16) = mw4;
    };
    meta_one(tid,       ox0, oy0, mv0);
    meta_one(tid + 256, ox1, oy1, mv1);
    if (has2) meta_one(tid + 512, ox2, oy2, mv2);
    __syncthreads();

    // ---- phase 3: wave = 16 px x 64 o-channels; single gather per corner ----
    int px3 = (w >> 1) * 32 + (w & 1) * 16 + col;   // this wave's pixel (by col)
    floatx4 acc[4];
    #pragma unroll
    for (int mt = 0; mt < 4; ++mt) acc[mt] = (floatx4){0.f, 0.f, 0.f, 0.f};

    int qk0 = quad * 16, qk1 = quad * 16 + 64;

    #pragma unroll
    for (int n = 0; n < 9; ++n) {
        uint4 mu = *(const uint4*)(s_meta + ((size_t)px3 * 9 + n) * 16);
        unsigned i0 = mu.x & 0xFFFFu, i1 = mu.x >> 16;
        unsigned i2 = mu.y & 0xFFFFu, i3 = mu.y >> 16;
        int pm0 = (i0 & 0x8000u) ? 0 : (int)i0;
        int pm1 = (i1 & 0x8000u) ? 0 : (int)i1;
        int pm2 = (i2 & 0x8000u) ? 0 : (int)i2;
        int pm3 = (i3 & 0x8000u) ? 0 : (int)i3;
        int b0 = pm0 << 7, s0 = (pm0 & 7) << 4;
        int b1 = pm1 << 7, s1 = (pm1 & 7) << 4;
        int b2 = pm2 << 7, s2 = (pm2 & 7) << 4;
        int b3 = pm3 << 7, s3 = (pm3 & 7) << 4;
        uint4 cA0 = *(const uint4*)(s_win + b0 + (qk0 ^ s0));
        uint4 cA1 = *(const uint4*)(s_win + b1 + (qk0 ^ s1));
        uint4 cA2 = *(const uint4*)(s_win + b2 + (qk0 ^ s2));
        uint4 cA3 = *(const uint4*)(s_win + b3 + (qk0 ^ s3));
        uint4 cB0 = *(const uint4*)(s_win + b0 + (qk1 ^ s0));
        uint4 cB1 = *(const uint4*)(s_win + b1 + (qk1 ^ s1));
        uint4 cB2 = *(const uint4*)(s_win + b2 + (qk1 ^ s2));
        uint4 cB3 = *(const uint4*)(s_win + b3 + (qk1 ^ s3));
        if (__any((int)((i0 | i1 | i2 | i3) & 0x8000u))) {
            // ultra-rare global fallback (slot overflow)
            if (i0 & 0x8000u) { size_t ga = (size_t)(i0 & 0x3FFFu) * 64 + quad * 8;
                cA0 = *(const uint4*)(xtb + ga); cB0 = *(const uint4*)(xtb + ga + 32); }
            if (i1 & 0x8000u) { size_t ga = (size_t)(i1 & 0x3FFFu) * 64 + quad * 8;
                cA1 = *(const uint4*)(xtb + ga); cB1 = *(const uint4*)(xtb + ga + 32); }
            if (i2 & 0x8000u) { size_t ga = (size_t)(i2 & 0x3FFFu) * 64 + quad * 8;
                cA2 = *(const uint4*)(xtb + ga); cB2 = *(const uint4*)(xtb + ga + 32); }
            if (i3 & 0x8000u) { size_t ga = (size_t)(i3 & 0x3FFFu) * 64 + quad * 8;
                cA3 = *(const uint4*)(xtb + ga); cB3 = *(const uint4*)(xtb + ga + 32); }
        }
        // splat each half g to a packed pair, then pure v_pk_mul/fma_f16
        unsigned gl0 = (mu.z & 0xFFFFu) | (mu.z << 16);
        unsigned gl1 = (mu.z >> 16) | (mu.z & 0xFFFF0000u);
        unsigned gl2 = (mu.w & 0xFFFFu) | (mu.w << 16);
        unsigned gl3 = (mu.w >> 16) | (mu.w & 0xFFFF0000u);
        halfx8 g0 = splat8(gl0), g1 = splat8(gl1), g2 = splat8(gl2), g3 = splat8(gl3);
        halfx8 vA = uph8(cA0) * g0;
        vA += uph8(cA1) * g1; vA += uph8(cA2) * g2; vA += uph8(cA3) * g3;
        halfx8 vB = uph8(cB0) * g0;
        vB += uph8(cB1) * g1; vB += uph8(cB2) * g2; vB += uph8(cB3) * g3;
        #pragma unroll
        for (int mt = 0; mt < 4; ++mt) {
            halfx8 afA = *(const halfx8*)(wfm + ((size_t)((n * 2 + 0) * 4 + mt) * 64 + lane) * 8);
            halfx8 afB = *(const halfx8*)(wfm + ((size_t)((n * 2 + 1) * 4 + mt) * 64 + lane) * 8);
            acc[mt] = __builtin_amdgcn_mfma_f32_16x16x32_f16(afA, vA, acc[mt], 0, 0, 0);
            acc[mt] = __builtin_amdgcn_mfma_f32_16x16x32_f16(afB, vB, acc[mt], 0, 0, 0);
        }
    }

    // ---- epilogue: wave writes 16 px x 64 o ----
    int sp = (hr + (w >> 1)) * 96 + wc + (w & 1) * 16 + col;
    #pragma unroll
    for (int mt = 0; mt < 4; ++mt) {
        float4 cb4 = *(const float4*)&convb[mt * 16 + quad * 4];
        #pragma unroll
        for (int r = 0; r < 4; ++r) {
            int o = mt * 16 + quad * 4 + r;
            float bias = (r == 0) ? cb4.x : (r == 1) ? cb4.y : (r == 2) ? cb4.z : cb4.w;
            out[(size_t)(bb * 64 + o) * HW_ + sp] = acc[mt][r] + bias;
        }
    }
}

// ---------------------------------------------------------------------------
extern "C" void kernel_launch(void* const* d_in, const int* in_sizes, int n_in,
                              void* d_out, int out_size, void* d_ws, size_t ws_size,
                              hipStream_t stream) {
    const float* x     = (const float*)d_in[0];
    const float* offw  = (const float*)d_in[1];
    const float* offb  = (const float*)d_in[2];
    const float* mw    = (const float*)d_in[3];
    const float* mb    = (const float*)d_in[4];
    const float* convw = (const float*)d_in[5];
    const float* convb = (const float*)d_in[6];
    char* ws = (char*)d_ws;
    unsigned short* xt16 = (unsigned short*)(ws + XT_OFF);
    unsigned short* wfm  = (unsigned short*)(ws + WFM_OFF);
    unsigned short* wfo  = (unsigned short*)(ws + WFO_OFF);
    unsigned short* wz   = (unsigned short*)(ws + WZ_OFF);
    float* out = (float*)d_out;

    k_transpose<<<dim3(1152 + 28), dim3(256), 0, stream>>>(x, xt16, offw, mw, convw, wfm, wfo, wz);
    k_fused    <<<dim3(1152),      dim3(256), 0, stream>>>(xt16, wfo, wfm, offb, mb, convb, wz, out);
}

// Round 9
// 109.292 us; speedup vs baseline: 1.3842x; 1.0031x over previous
//
#include <hip/hip_runtime.h>
#include <hip/hip_fp16.h>
#include <cstddef>

#define B_   8
#define H_   96
#define W_   96
#define HW_  9216
#define PIX_ 73728

// LDS window geometry: rows hr-2..hr+4 (7), cols wc-3..wc+34 (38)
#define NWR    7
#define NWC    38
#define WINPX  266
#define NSLOTS 19

typedef __attribute__((ext_vector_type(8))) _Float16 halfx8;
typedef __attribute__((ext_vector_type(2))) __fp16 fp16x2_raw;
typedef __attribute__((ext_vector_type(4))) float floatx4;

// ws layout (byte offsets)
#define XT_OFF   0                          // fp16 NHWC x: PIX*64*2
#define WFM_OFF  (XT_OFF + PIX_*64*2)       // main W frags: 18*4*64*8 fp16
#define WFO_OFF  (WFM_OFF + 18*4*64*8*2)    // offs W frags: 18*2*64*8 fp16
#define WZ_OFF   (WFO_OFF + 18*2*64*8*2)    // 128B zero page

__device__ __forceinline__ unsigned pk2h(float a, float b) {
    fp16x2_raw h = __builtin_amdgcn_cvt_pkrtz(a, b);
    union { fp16x2_raw h2; unsigned u; } t; t.h2 = h; return t.u;
}
__device__ __forceinline__ halfx8 uph8(uint4 u) {
    union { uint4 u4; halfx8 h; } t; t.u4 = u; return t.h;
}
__device__ __forceinline__ halfx8 splat8(unsigned d) {
    union { unsigned u[4]; halfx8 h; } t;
    t.u[0] = d; t.u[1] = d; t.u[2] = d; t.u[3] = d; return t.h;
}
__device__ __forceinline__ void async_ld16(const void* g, void* l) {
    __builtin_amdgcn_global_load_lds((const __attribute__((address_space(1))) void*)g,
                                     (__attribute__((address_space(3))) void*)l,
                                     16, 0, 0);
}

// ---------------------------------------------------------------------------
// NCHW f32 -> NHWC fp16 transpose via LDS tile; tail blocks pack weights.
__global__ __launch_bounds__(256) void k_transpose(const float* __restrict__ x,
                                                   unsigned short* __restrict__ xt,
                                                   const float* __restrict__ offw,
                                                   const float* __restrict__ mw,
                                                   const float* __restrict__ convw,
                                                   unsigned short* __restrict__ wfm,
                                                   unsigned short* __restrict__ wfo,
                                                   unsigned short* __restrict__ wz) {
    if (blockIdx.x >= 1152) {
        // ---- weight-prep branch (28 blocks) ----
        int g = (blockIdx.x - 1152) * 256 + threadIdx.x;
        if (g < 4608) {
            int lane = g & 63, mtks = g >> 6;
            int mt = mtks & 3, ks = mtks >> 2;
            int o = mt * 16 + (lane & 15), quad = lane >> 4;
            float v[8];
            #pragma unroll
            for (int j = 0; j < 8; ++j) {
                int k = ks * 32 + quad * 8 + j;
                int t = k / 64, c = k % 64;
                v[j] = convw[(size_t)(o * 64 + c) * 9 + t];
            }
            uint4 pk;
            pk.x = pk2h(v[0], v[1]); pk.y = pk2h(v[2], v[3]);
            pk.z = pk2h(v[4], v[5]); pk.w = pk2h(v[6], v[7]);
            *(uint4*)(wfm + (size_t)g * 8) = pk;
        } else if (g < 4608 + 2304) {
            int g2 = g - 4608;
            int lane = g2 & 63, mtks = g2 >> 6;
            int mt = mtks & 1, ks = mtks >> 1;
            int m = mt * 16 + (lane & 15), quad = lane >> 4;
            float v[8];
            #pragma unroll
            for (int j = 0; j < 8; ++j) {
                int k = ks * 32 + quad * 8 + j;
                int t = k / 64, c = k % 64;
                float f = 0.f;
                if (m < 18)      f = offw[(size_t)(m * 64 + c) * 9 + t];
                else if (m < 27) f = mw[(size_t)((m - 18) * 64 + c) * 9 + t];
                v[j] = f;
            }
            uint4 pk;
            pk.x = pk2h(v[0], v[1]); pk.y = pk2h(v[2], v[3]);
            pk.z = pk2h(v[4], v[5]); pk.w = pk2h(v[6], v[7]);
            *(uint4*)(wfo + (size_t)g2 * 8) = pk;
        } else if (g < 4608 + 2304 + 8) {
            // zero page (128 B)
            uint4 z = make_uint4(0, 0, 0, 0);
            *(uint4*)(wz + (size_t)(g - 6912) * 8) = z;
        }
        return;
    }

    __shared__ float tile[64 * 65];
    int bb  = blockIdx.x / 144;
    int sp0 = (blockIdx.x % 144) * 64;
    int t = threadIdx.x;
    int s4 = (t & 15) * 4, cq = t >> 4;
    #pragma unroll
    for (int i = 0; i < 4; ++i) {
        int c = cq + 16 * i;
        float4 v = *(const float4*)&x[(size_t)(bb * 64 + c) * HW_ + sp0 + s4];
        tile[c * 65 + s4 + 0] = v.x;
        tile[c * 65 + s4 + 1] = v.y;
        tile[c * 65 + s4 + 2] = v.z;
        tile[c * 65 + s4 + 3] = v.w;
    }
    __syncthreads();
    // each lane packs 8 channels of one pixel -> 1KB contiguous per wave-store
    int c8 = t & 7, sgrp = t >> 3;      // sgrp 0..31
    #pragma unroll
    for (int i = 0; i < 2; ++i) {
        int s2 = i * 32 + sgrp;
        uint4 pk;
        pk.x = pk2h(tile[(c8 * 8 + 0) * 65 + s2], tile[(c8 * 8 + 1) * 65 + s2]);
        pk.y = pk2h(tile[(c8 * 8 + 2) * 65 + s2], tile[(c8 * 8 + 3) * 65 + s2]);
        pk.z = pk2h(tile[(c8 * 8 + 4) * 65 + s2], tile[(c8 * 8 + 5) * 65 + s2]);
        pk.w = pk2h(tile[(c8 * 8 + 6) * 65 + s2], tile[(c8 * 8 + 7) * 65 + s2]);
        *(uint4*)(xt + (size_t)(bb * HW_ + sp0 + s2) * 64 + c8 * 8) = pk;
    }
}

// ---------------------------------------------------------------------------
// Fused kernel. Block = 384 thr = 6 waves, owns 96 px (3 rows x 32 cols).
// 768 blocks total = 3 blocks/CU x 256 CU -> EXACTLY one dispatch round.
// 7x38 window DMA'd to LDS; s_off aliased onto s_meta; wave = 16 px x 64 o.
__global__ __launch_bounds__(384, 4) void k_fused(const unsigned short* __restrict__ xt,
                                                  const unsigned short* __restrict__ wfo,
                                                  const unsigned short* __restrict__ wfm,
                                                  const float* __restrict__ offb,
                                                  const float* __restrict__ mb,
                                                  const float* __restrict__ convb,
                                                  const unsigned short* __restrict__ wz,
                                                  float* __restrict__ out) {
    __shared__ __align__(16) unsigned char s_win[(WINPX + NSLOTS) * 128];  // 36480 B
    __shared__ __align__(16) unsigned char s_u[96 * 9 * 16];               // 13824 B union
    __shared__ int s_cnt;
    float* s_off = (float*)s_u;            // 27 x 98 f32 (phase 1-2) = 10584 B
    unsigned char* s_meta = s_u;           // 96 x 9 x 16 B (phase 2-3)

    int tid = threadIdx.x;
    int w = tid >> 6, lane = tid & 63, col = lane & 15, quad = lane >> 4;
    // XCD-aware swizzle: each XCD owns one batch region (768 = 8 x 96)
    int blk = (blockIdx.x & 7) * 96 + (blockIdx.x >> 3);
    int bb  = blk / 96;
    int rem = blk % 96;
    int hr  = (rem / 3) * 3;            // top row of the 3-row tile
    int wc  = (rem % 3) * 32;           // left col of the 32-col segment
    const unsigned short* xtb = xt + (size_t)bb * HW_ * 64;

    // ---- stage window: direct-to-LDS DMA, source pre-swizzled; OOB -> zeros ----
    if (tid == 0) s_cnt = 0;
    {
        int p0  = lane >> 3;                    // pixel-within-group
        int cgx = (lane & 7) ^ p0;              // swizzled source ch-group
        const unsigned short* wzp = wz + cgx * 8;
        for (int i = w; i < 34; i += 6) {       // 34 groups of 8 px, split by wave
            int p = i * 8 + p0;
            int wr = p / NWC, wcl = p - wr * NWC;
            int gr = hr - 2 + wr, gc = wc - 3 + wcl;
            bool ok = (p < WINPX) && ((unsigned)gr < 96u) && ((unsigned)gc < 96u);
            const unsigned short* src = ok ? (xtb + ((size_t)(gr * 96 + gc) * 64 + cgx * 8)) : wzp;
            async_ld16(src, s_win + i * 1024);
        }
    }
    __syncthreads();

    // ---- phase 1: offset/mod conv GEMM (B from LDS window) ----
    // wave w: 16 px at (row hr + (w>>1), cols wc + (w&1)*16 + col)
    floatx4 aoff0 = (floatx4){0.f, 0.f, 0.f, 0.f};
    floatx4 aoff1 = (floatx4){0.f, 0.f, 0.f, 0.f};
    {
        int wr_base = 2 + (w >> 1);
        int wc_base = 3 + (w & 1) * 16 + col;
        #pragma unroll
        for (int t = 0; t < 9; ++t) {
            int dh = t / 3 - 1, dw = t % 3 - 1;
            int p = (wr_base + dh) * NWC + (wc_base + dw);
            int pb = p << 7, psw = (p & 7) << 4;
            #pragma unroll
            for (int ksl = 0; ksl < 2; ++ksl) {
                int ks = t * 2 + ksl;
                halfx8 a0 = *(const halfx8*)(wfo + ((size_t)(ks * 2 + 0) * 64 + lane) * 8);
                halfx8 a1 = *(const halfx8*)(wfo + ((size_t)(ks * 2 + 1) * 64 + lane) * 8);
                uint4 bvu = *(const uint4*)(s_win + pb + ((quad * 16 + ksl * 64) ^ psw));
                halfx8 bv = uph8(bvu);
                aoff0 = __builtin_amdgcn_mfma_f32_16x16x32_f16(a0, bv, aoff0, 0, 0, 0);
                aoff1 = __builtin_amdgcn_mfma_f32_16x16x32_f16(a1, bv, aoff1, 0, 0, 0);
            }
        }
    }
    #pragma unroll
    for (int r = 0; r < 4; ++r) {
        s_off[(quad * 4 + r) * 98 + (w * 16 + col)] = aoff0[r];
        int m = 16 + quad * 4 + r;
        if (m < 27) s_off[m * 98 + (w * 16 + col)] = aoff1[r];
    }
    __syncthreads();

    // ---- phase 2a: read s_off (+bias) into static registers (864 items) ----
    float ox0, oy0, mv0, ox1, oy1, mv1, ox2 = 0.f, oy2 = 0.f, mv2 = 0.f;
    bool has2 = tid < 96;               // 864 - 768
    {
        int px = tid % 96, n = tid / 96;
        ox0 = s_off[n * 98 + px]        + offb[n];
        oy0 = s_off[(9 + n) * 98 + px]  + offb[9 + n];
        mv0 = s_off[(18 + n) * 98 + px] + mb[n];
    }
    {
        int id = tid + 384;
        int px = id % 96, n = id / 96;
        ox1 = s_off[n * 98 + px]        + offb[n];
        oy1 = s_off[(9 + n) * 98 + px]  + offb[9 + n];
        mv1 = s_off[(18 + n) * 98 + px] + mb[n];
    }
    if (has2) {
        int id = tid + 768;
        int px = id % 96, n = id / 96;
        ox2 = s_off[n * 98 + px]        + offb[n];
        oy2 = s_off[(9 + n) * 98 + px]  + offb[9 + n];
        mv2 = s_off[(18 + n) * 98 + px] + mb[n];
    }
    __syncthreads();   // s_off fully read; s_u becomes s_meta

    // ---- phase 2b: bilinear metadata (s_meta aliases s_off's space) ----
    auto meta_one = [&](int id, float ox, float oy, float mv) {
        int px = id % 96, n = id / 96;
        float modv = 1.f / (1.f + __expf(-mv));
        int prow = hr + (px >> 5), pcol = wc + (px & 31);
        float pxx = ox + (float)(prow + 1) + (float)(n / 3 - 1);
        float pyy = oy + (float)(pcol + 1) + (float)(n % 3 - 1);
        float flx = floorf(pxx), fly = floorf(pyy);
        float tlxf = fminf(fmaxf(flx,       0.f), 97.f);
        float tlyf = fminf(fmaxf(fly,       0.f), 97.f);
        float brxf = fminf(fmaxf(flx + 1.f, 0.f), 97.f);
        float bryf = fminf(fmaxf(fly + 1.f, 0.f), 97.f);
        float pcx  = fminf(fmaxf(pxx, 0.f), 97.f);
        float pcy  = fminf(fmaxf(pyy, 0.f), 97.f);
        float gx0 = 1.f + tlxf - pcx;
        float gx1 = 1.f - (brxf - pcx);
        float gy0 = 1.f + tlyf - pcy;
        float gy1 = 1.f - (bryf - pcy);
        int tlx = (int)tlxf, tly = (int)tlyf, brx = (int)brxf, bry = (int)bryf;
        int   qxs[4] = {tlx, tlx, brx, brx};
        int   qys[4] = {tly, bry, tly, bry};
        float gs4[4] = {gx0 * gy0, gx0 * gy1, gx1 * gy0, gx1 * gy1};
        unsigned short si[4]; unsigned short hg[4];
        #pragma unroll
        for (int c4 = 0; c4 < 4; ++c4) {
            int qx = qxs[c4], qy = qys[c4];
            bool valid = (qx >= 1) && (qx <= 96) && (qy >= 1) && (qy <= 96);
            int gr = qx - 1, gc = qy - 1;
            int wr = gr - (hr - 2), wcl = gc - (wc - 3);
            bool inwin = ((unsigned)wr < (unsigned)NWR) && ((unsigned)wcl < (unsigned)NWC);
            unsigned short idxv; float gvf;
            if (inwin) {
                idxv = (unsigned short)(wr * NWC + wcl);   // zeros staged for out-of-image
                gvf = gs4[c4] * modv;
            } else if (!valid) {
                idxv = 0; gvf = 0.f;
            } else {
                // rare: valid corner outside window -> copy into LDS overflow slot
                int s = atomicAdd(&s_cnt, 1);
                int gidx = gr * 96 + gc;
                if (s < NSLOTS) {
                    int ps = WINPX + s;
                    #pragma unroll
                    for (int ch = 0; ch < 8; ++ch) {
                        uint4 v = *(const uint4*)(xtb + (size_t)gidx * 64 + ch * 8);
                        *(uint4*)(s_win + (size_t)ps * 128 + ((ch ^ (ps & 7)) * 16)) = v;
                    }
                    idxv = (unsigned short)ps;
                } else {
                    idxv = (unsigned short)(0x8000u | (unsigned)gidx);  // global fallback tag
                }
                gvf = gs4[c4] * modv;
            }
            si[c4] = idxv;
            hg[c4] = __half_as_ushort(__float2half_rn(gvf));
        }
        uint4 mw4;
        mw4.x = si[0] | ((unsigned)si[1] << 16);
        mw4.y = si[2] | ((unsigned)si[3] << 16);
        mw4.z = hg[0] | ((unsigned)hg[1] << 16);
        mw4.w = hg[2] | ((unsigned)hg[3] << 16);
        *(uint4*)(s_meta + ((size_t)px * 9 + n) * 16) = mw4;
    };
    meta_one(tid,       ox0, oy0, mv0);
    meta_one(tid + 384, ox1, oy1, mv1);
    if (has2) meta_one(tid + 768, ox2, oy2, mv2);
    __syncthreads();

    // ---- phase 3: wave = 16 px x 64 o-channels; single gather per corner ----
    int px3 = w * 16 + col;            // this wave's pixel
    floatx4 acc[4];
    #pragma unroll
    for (int mt = 0; mt < 4; ++mt) acc[mt] = (floatx4){0.f, 0.f, 0.f, 0.f};

    int qk0 = quad * 16, qk1 = quad * 16 + 64;

    #pragma unroll
    for (int n = 0; n < 9; ++n) {
        uint4 mu = *(const uint4*)(s_meta + ((size_t)px3 * 9 + n) * 16);
        unsigned i0 = mu.x & 0xFFFFu, i1 = mu.x >> 16;
        unsigned i2 = mu.y & 0xFFFFu, i3 = mu.y >> 16;
        int pm0 = (i0 & 0x8000u) ? 0 : (int)i0;
        int pm1 = (i1 & 0x8000u) ? 0 : (int)i1;
        int pm2 = (i2 & 0x8000u) ? 0 : (int)i2;
        int pm3 = (i3 & 0x8000u) ? 0 : (int)i3;
        int b0 = pm0 << 7, s0 = (pm0 & 7) << 4;
        int b1 = pm1 << 7, s1 = (pm1 & 7) << 4;
        int b2 = pm2 << 7, s2 = (pm2 & 7) << 4;
        int b3 = pm3 << 7, s3 = (pm3 & 7) << 4;
        uint4 cA0 = *(const uint4*)(s_win + b0 + (qk0 ^ s0));
        uint4 cA1 = *(const uint4*)(s_win + b1 + (qk0 ^ s1));
        uint4 cA2 = *(const uint4*)(s_win + b2 + (qk0 ^ s2));
        uint4 cA3 = *(const uint4*)(s_win + b3 + (qk0 ^ s3));
        uint4 cB0 = *(const uint4*)(s_win + b0 + (qk1 ^ s0));
        uint4 cB1 = *(const uint4*)(s_win + b1 + (qk1 ^ s1));
        uint4 cB2 = *(const uint4*)(s_win + b2 + (qk1 ^ s2));
        uint4 cB3 = *(const uint4*)(s_win + b3 + (qk1 ^ s3));
        if (__any((int)((i0 | i1 | i2 | i3) & 0x8000u))) {
            // ultra-rare global fallback (slot overflow)
            if (i0 & 0x8000u) { size_t ga = (size_t)(i0 & 0x3FFFu) * 64 + quad * 8;
                cA0 = *(const uint4*)(xtb + ga); cB0 = *(const uint4*)(xtb + ga + 32); }
            if (i1 & 0x8000u) { size_t ga = (size_t)(i1 & 0x3FFFu) * 64 + quad * 8;
                cA1 = *(const uint4*)(xtb + ga); cB1 = *(const uint4*)(xtb + ga + 32); }
            if (i2 & 0x8000u) { size_t ga = (size_t)(i2 & 0x3FFFu) * 64 + quad * 8;
                cA2 = *(const uint4*)(xtb + ga); cB2 = *(const uint4*)(xtb + ga + 32); }
            if (i3 & 0x8000u) { size_t ga = (size_t)(i3 & 0x3FFFu) * 64 + quad * 8;
                cA3 = *(const uint4*)(xtb + ga); cB3 = *(const uint4*)(xtb + ga + 32); }
        }
        // splat each half g to a packed pair, then pure v_pk_mul/fma_f16
        unsigned gl0 = (mu.z & 0xFFFFu) | (mu.z << 16);
        unsigned gl1 = (mu.z >> 16) | (mu.z & 0xFFFF0000u);
        unsigned gl2 = (mu.w & 0xFFFFu) | (mu.w << 16);
        unsigned gl3 = (mu.w >> 16) | (mu.w & 0xFFFF0000u);
        halfx8 g0 = splat8(gl0), g1 = splat8(gl1), g2 = splat8(gl2), g3 = splat8(gl3);
        halfx8 vA = uph8(cA0) * g0;
        vA += uph8(cA1) * g1; vA += uph8(cA2) * g2; vA += uph8(cA3) * g3;
        halfx8 vB = uph8(cB0) * g0;
        vB += uph8(cB1) * g1; vB += uph8(cB2) * g2; vB += uph8(cB3) * g3;
        #pragma unroll
        for (int mt = 0; mt < 4; ++mt) {
            halfx8 afA = *(const halfx8*)(wfm + ((size_t)((n * 2 + 0) * 4 + mt) * 64 + lane) * 8);
            halfx8 afB = *(const halfx8*)(wfm + ((size_t)((n * 2 + 1) * 4 + mt) * 64 + lane) * 8);
            acc[mt] = __builtin_amdgcn_mfma_f32_16x16x32_f16(afA, vA, acc[mt], 0, 0, 0);
            acc[mt] = __builtin_amdgcn_mfma_f32_16x16x32_f16(afB, vB, acc[mt], 0, 0, 0);
        }
    }

    // ---- epilogue: wave writes 16 px x 64 o ----
    int sp = (hr + (w >> 1)) * 96 + wc + (w & 1) * 16 + col;
    #pragma unroll
    for (int mt = 0; mt < 4; ++mt) {
        float4 cb4 = *(const float4*)&convb[mt * 16 + quad * 4];
        #pragma unroll
        for (int r = 0; r < 4; ++r) {
            int o = mt * 16 + quad * 4 + r;
            float bias = (r == 0) ? cb4.x : (r == 1) ? cb4.y : (r == 2) ? cb4.z : cb4.w;
            out[(size_t)(bb * 64 + o) * HW_ + sp] = acc[mt][r] + bias;
        }
    }
}

// ---------------------------------------------------------------------------
extern "C" void kernel_launch(void* const* d_in, const int* in_sizes, int n_in,
                              void* d_out, int out_size, void* d_ws, size_t ws_size,
                              hipStream_t stream) {
    const float* x     = (const float*)d_in[0];
    const float* offw  = (const float*)d_in[1];
    const float* offb  = (const float*)d_in[2];
    const float* mw    = (const float*)d_in[3];
    const float* mb    = (const float*)d_in[4];
    const float* convw = (const float*)d_in[5];
    const float* convb = (const float*)d_in[6];
    char* ws = (char*)d_ws;
    unsigned short* xt16 = (unsigned short*)(ws + XT_OFF);
    unsigned short* wfm  = (unsigned short*)(ws + WFM_OFF);
    unsigned short* wfo  = (unsigned short*)(ws + WFO_OFF);
    unsigned short* wz   = (unsigned short*)(ws + WZ_OFF);
    float* out = (float*)d_out;

    k_transpose<<<dim3(1152 + 28), dim3(256), 0, stream>>>(x, xt16, offw, mw, convw, wfm, wfo, wz);
    k_fused    <<<dim3(768),       dim3(384), 0, stream>>>(xt16, wfo, wfm, offb, mb, convb, wz, out);
}